// Round 12
// baseline (488.369 us; speedup 1.0000x reference)
//
#include <hip/hip_runtime.h>
#include <hip/hip_bf16.h>

#define NN 20000
#define EE 320000
#define LGN 4

typedef unsigned short u16;
typedef short bf16x8 __attribute__((ext_vector_type(8)));
typedef float f32x4 __attribute__((ext_vector_type(4)));

__device__ __forceinline__ float bf2f(u16 v) {
    unsigned int u = ((unsigned int)v) << 16;
    float f; __builtin_memcpy(&f, &u, 4); return f;
}
__device__ __forceinline__ u16 f2bf(float f) {
    __hip_bfloat16 h = __float2bfloat16(f);
    u16 u; __builtin_memcpy(&u, &h, 2); return u;
}

// async global->LDS, 16B per lane, LDS dest = wave-uniform base + lane*16
__device__ __forceinline__ void gll16(const void* g, void* l) {
    __builtin_amdgcn_global_load_lds(
        (const __attribute__((address_space(1))) unsigned int*)g,
        (__attribute__((address_space(3))) unsigned int*)l, 16, 0, 0);
}

// ---- pass 1: degree (by source), col histogram, ew copy-out, pad-zero ----
__global__ __launch_bounds__(256) void k_edge1(const int* __restrict__ ei,
                                               const float* __restrict__ ew,
                                               float* __restrict__ deg,
                                               int* __restrict__ counts,
                                               float* __restrict__ out_ew,
                                               int2* __restrict__ nbrs) {
    int e = blockIdx.x * 256 + threadIdx.x;
    if (blockIdx.x == 0 && threadIdx.x < 16)
        nbrs[EE + threadIdx.x] = make_int2(0, 0);  // gather-overrun pad
    if (e >= EE) return;
    int r = ei[e];
    float w = ew[e];
    atomicAdd(&deg[r], w);
    atomicAdd(&counts[ei[EE + e]], 1);
    out_ew[e] = w;
}

// ---- exclusive scan of col histogram (single block) ----
__global__ __launch_bounds__(1024) void k_scan(const int* __restrict__ counts,
                                               int* __restrict__ offs) {
    __shared__ int part[1024];
    int t = threadIdx.x;
    const int C = (NN + 1023) / 1024;  // 20
    int lo = t * C, hi = min(lo + C, NN);
    int s = 0;
    for (int i = lo; i < hi; i++) s += counts[i];
    part[t] = s;
    __syncthreads();
    for (int off = 1; off < 1024; off <<= 1) {
        int add = (t >= off) ? part[t - off] : 0;
        __syncthreads();
        part[t] += add;
        __syncthreads();
    }
    int base = part[t] - s;
    for (int i = lo; i < hi; i++) { offs[i] = base; base += counts[i]; }
    if (t == 1023) offs[NN] = part[1023];
}

// ---- pass 2: compute norm (rsqrt folded in), scatter into CSR slots ----
__global__ __launch_bounds__(256) void k_scatter(const int* __restrict__ ei,
                                                 const float* __restrict__ ew,
                                                 const float* __restrict__ deg,
                                                 const int* __restrict__ offs,
                                                 int* __restrict__ cursor,
                                                 int2* __restrict__ nbrs) {
    int e = blockIdx.x * 256 + threadIdx.x;
    if (e >= EE) return;
    int r = ei[e], c = ei[EE + e];
    float dr = deg[r], dc = deg[c];
    float ir = (dr > 0.f) ? rsqrtf(dr) : 0.f;
    float ic = (dc > 0.f) ? rsqrtf(dc) : 0.f;
    float nm = -(ir * ew[e] * ic);
    int pidx = offs[c] + atomicAdd(&cursor[c], 1);
    nbrs[pidx] = make_int2(r, __float_as_int(nm));
}

// ---- fragment-tile helpers: one 16B chunk of Bf layout from f32 [K][256] ----
// chunk u: lane l=u&63, n-frag f=(u>>6)&15, k-step s=u>>10;
// holds B[col=f*16+(l&15)][k=s*32+(l>>4)*8 .. +7].
__device__ __forceinline__ void castB_chunk(const float* __restrict__ src,
                                            u16* __restrict__ dst, int u) {
    int l = u & 63, f = (u >> 6) & 15, s = u >> 10;
    int col = f * 16 + (l & 15);
    int kb = s * 32 + ((l >> 4) << 3);
    u16 tmp[8];
#pragma unroll
    for (int j = 0; j < 8; j++) tmp[j] = f2bf(src[(size_t)(kb + j) * 256 + col]);
    *(uint4*)(dst + (size_t)u * 8) = *(uint4*)tmp;
}

// cheb variant with the R21 WEIGHT FOLD: the fused gemm consumes y = L·tx1
// raw (not tx2 = 2y - x), so W0' = W0 - W2, W1' = W1, W2' = 2*W2 keeps
// x@W0' + tx1@W1' + y@W2' == x@W0 + tx1@W1 + tx2@W2 exactly (fp32 fold).
__device__ __forceinline__ void castB_chunk_cheb(const float* __restrict__ src,
                                                 u16* __restrict__ dst, int u) {
    int l = u & 63, f = (u >> 6) & 15, s = u >> 10;
    int col = f * 16 + (l & 15);
    int kb = s * 32 + ((l >> 4) << 3);
    u16 tmp[8];
#pragma unroll
    for (int j = 0; j < 8; j++) {
        int k = kb + j;
        float v;
        if (k < 256)       v = src[(size_t)k * 256 + col] - src[(size_t)(k + 512) * 256 + col];
        else if (k < 512)  v = src[(size_t)k * 256 + col];
        else               v = 2.f * src[(size_t)k * 256 + col];
        tmp[j] = f2bf(v);
    }
    *(uint4*)(dst + (size_t)u * 8) = *(uint4*)tmp;
}

// ---- fused prep: features cast + chebT castB x4 (folded) + w1T + foldbn ----
__global__ __launch_bounds__(256) void k_prep(
    const float* __restrict__ features, u16* __restrict__ xb,
    const float* __restrict__ cheb_w, u16* __restrict__ chebT,
    const float* __restrict__ w1, u16* __restrict__ w1T,
    const float* __restrict__ g, const float* __restrict__ be,
    const float* __restrict__ mn, const float* __restrict__ vr,
    float* __restrict__ sc, float* __restrict__ sh) {
    int tid = blockIdx.x * 256 + threadIdx.x;
    if (tid < NN * 256) {
        xb[tid] = f2bf(features[tid]);
        return;
    }
    tid -= NN * 256;
    if (tid < 4 * 24576) {  // chebT: 4 weight sets, K=768 -> 24576 chunks each
        int set = tid / 24576, u = tid - set * 24576;
        castB_chunk_cheb(cheb_w + (size_t)set * 768 * 256, chebT + (size_t)set * 768 * 256, u);
        return;
    }
    tid -= 4 * 24576;
    if (tid < 32768) {  // w1T: K=1024 -> 32768 chunks
        castB_chunk(w1, w1T, tid);
        return;
    }
    tid -= 32768;
    if (tid < 256) {  // fold BN affine
        float s = g[tid] * rsqrtf(vr[tid] + 1e-5f);
        sc[tid] = s;
        sh[tid] = be[tid] - mn[tid] * s;
    }
}

// ---- CSR SpMM: one WAVE per node (R18 ceil-4 form; dotx2 path removed) ----
__global__ __launch_bounds__(256) void k_prop(const u16* __restrict__ x, int ldx,
                                              u16* __restrict__ out,
                                              const int* __restrict__ offs,
                                              const int2* __restrict__ nbrs) {
    int c = __builtin_amdgcn_readfirstlane(blockIdx.x * 4 + (threadIdx.x >> 6));
    int lane = threadIdx.x & 63;
    int s = offs[c], e = offs[c + 1];
    float a0 = 0.f, a1 = 0.f, a2 = 0.f, a3 = 0.f;
    for (int i = s; i < e; i += 16) {
        int2 mm[16];
        ushort4 xv[16];
        bool g1 = (i + 4 < e), g2 = (i + 8 < e), g3 = (i + 12 < e);  // wave-uniform
#pragma unroll
        for (int j = 0; j < 4; j++) mm[j] = nbrs[i + j];
        if (g1) {
#pragma unroll
            for (int j = 4; j < 8; j++) mm[j] = nbrs[i + j];
        }
        if (g2) {
#pragma unroll
            for (int j = 8; j < 12; j++) mm[j] = nbrs[i + j];
        }
        if (g3) {
#pragma unroll
            for (int j = 12; j < 16; j++) mm[j] = nbrs[i + j];
        }
#pragma unroll
        for (int j = 0; j < 4; j++)
            xv[j] = *(const ushort4*)(x + (size_t)mm[j].x * ldx + lane * 4);
        if (g1) {
#pragma unroll
            for (int j = 4; j < 8; j++)
                xv[j] = *(const ushort4*)(x + (size_t)mm[j].x * ldx + lane * 4);
        }
        if (g2) {
#pragma unroll
            for (int j = 8; j < 12; j++)
                xv[j] = *(const ushort4*)(x + (size_t)mm[j].x * ldx + lane * 4);
        }
        if (g3) {
#pragma unroll
            for (int j = 12; j < 16; j++)
                xv[j] = *(const ushort4*)(x + (size_t)mm[j].x * ldx + lane * 4);
        }
#pragma unroll
        for (int j = 0; j < 4; j++) {
            float w = (i + j < e) ? __int_as_float(mm[j].y) : 0.f;
            a0 += w * bf2f(xv[j].x);
            a1 += w * bf2f(xv[j].y);
            a2 += w * bf2f(xv[j].z);
            a3 += w * bf2f(xv[j].w);
        }
        if (g1) {
#pragma unroll
            for (int j = 4; j < 8; j++) {
                float w = (i + j < e) ? __int_as_float(mm[j].y) : 0.f;
                a0 += w * bf2f(xv[j].x);
                a1 += w * bf2f(xv[j].y);
                a2 += w * bf2f(xv[j].z);
                a3 += w * bf2f(xv[j].w);
            }
        }
        if (g2) {
#pragma unroll
            for (int j = 8; j < 12; j++) {
                float w = (i + j < e) ? __int_as_float(mm[j].y) : 0.f;
                a0 += w * bf2f(xv[j].x);
                a1 += w * bf2f(xv[j].y);
                a2 += w * bf2f(xv[j].z);
                a3 += w * bf2f(xv[j].w);
            }
        }
        if (g3) {
#pragma unroll
            for (int j = 12; j < 16; j++) {
                float w = (i + j < e) ? __int_as_float(mm[j].y) : 0.f;
                a0 += w * bf2f(xv[j].x);
                a1 += w * bf2f(xv[j].y);
                a2 += w * bf2f(xv[j].z);
                a3 += w * bf2f(xv[j].w);
            }
        }
    }
    ushort4 o;
    o.x = f2bf(a0); o.y = f2bf(a1); o.z = f2bf(a2); o.w = f2bf(a3);
    *(ushort4*)(out + (size_t)c * 256 + lane * 4) = o;
}

// ---- R21 fused MFMA GEMM: phase0 inline-prop (y = L·tx1 for own 32 rows
// -> LDS [32][264]) + 16 piped K-steps (A0=x, A1=tx1 via gll16) + 8 LDS
// K-steps (y). Weights pre-folded (see castB_chunk_cheb). mode 0: relu ->
// jk slice. mode 2: + classifier phase B (K=1024: jk 0-2 piped + h3 LDS)
// + BN/w2 epilogue -> logits. Saves per layer: prop2 dispatch + y write
// + tx2 re-read + xsub read (~30 MB + 1 boundary).
__global__ __launch_bounds__(128, 2) void k_gemm(
    const u16* __restrict__ A0, int lda0,
    const u16* __restrict__ TX,  // tx1, ld 256: A1 + phase-0 gather source
    const int* __restrict__ offs, const int2* __restrict__ nbrs,
    const u16* __restrict__ Bf, const u16* __restrict__ Bf2,
    const u16* __restrict__ jkb,
    int mode, u16* __restrict__ outb,
    const float* __restrict__ bias, const float* __restrict__ sc,
    const float* __restrict__ sh, const float* __restrict__ w2,
    const float* __restrict__ b2, float* __restrict__ outlog) {
    // u16 offsets: A-bufs [0,4096) (4 x 2KB); Y [4096,12544) = [32][264];
    // H3 [12544,20992) = [32][264] (mode 2). 41984 B total.
    __shared__ __align__(16) u16 lds[20992];
    int t = threadIdx.x;
    int wv = t >> 6, l = t & 63;
    int q = l >> 4, l16 = l & 15;
    int m0 = blockIdx.x * 32;
    int n0 = wv * 128;
    u16* Y = lds + 4096;
    u16* H3 = lds + 12544;

    // ---- phase 0: y = L·tx1 for rows m0+wv*16 .. +15 -> Y ----
    for (int r = 0; r < 16; r++) {
        int c = m0 + wv * 16 + r;  // wave-uniform
        int s0 = offs[c], e0 = offs[c + 1];
        float a0 = 0.f, a1 = 0.f, a2 = 0.f, a3 = 0.f;
        for (int i = s0; i < e0; i += 16) {
            int2 mm[16];
            ushort4 xv[16];
            bool g1 = (i + 4 < e0), g2 = (i + 8 < e0), g3 = (i + 12 < e0);
#pragma unroll
            for (int j = 0; j < 4; j++) mm[j] = nbrs[i + j];
            if (g1) {
#pragma unroll
                for (int j = 4; j < 8; j++) mm[j] = nbrs[i + j];
            }
            if (g2) {
#pragma unroll
                for (int j = 8; j < 12; j++) mm[j] = nbrs[i + j];
            }
            if (g3) {
#pragma unroll
                for (int j = 12; j < 16; j++) mm[j] = nbrs[i + j];
            }
#pragma unroll
            for (int j = 0; j < 4; j++)
                xv[j] = *(const ushort4*)(TX + (size_t)mm[j].x * 256 + l * 4);
            if (g1) {
#pragma unroll
                for (int j = 4; j < 8; j++)
                    xv[j] = *(const ushort4*)(TX + (size_t)mm[j].x * 256 + l * 4);
            }
            if (g2) {
#pragma unroll
                for (int j = 8; j < 12; j++)
                    xv[j] = *(const ushort4*)(TX + (size_t)mm[j].x * 256 + l * 4);
            }
            if (g3) {
#pragma unroll
                for (int j = 12; j < 16; j++)
                    xv[j] = *(const ushort4*)(TX + (size_t)mm[j].x * 256 + l * 4);
            }
#pragma unroll
            for (int j = 0; j < 4; j++) {
                float w = (i + j < e0) ? __int_as_float(mm[j].y) : 0.f;
                a0 += w * bf2f(xv[j].x);
                a1 += w * bf2f(xv[j].y);
                a2 += w * bf2f(xv[j].z);
                a3 += w * bf2f(xv[j].w);
            }
            if (g1) {
#pragma unroll
                for (int j = 4; j < 8; j++) {
                    float w = (i + j < e0) ? __int_as_float(mm[j].y) : 0.f;
                    a0 += w * bf2f(xv[j].x);
                    a1 += w * bf2f(xv[j].y);
                    a2 += w * bf2f(xv[j].z);
                    a3 += w * bf2f(xv[j].w);
                }
            }
            if (g2) {
#pragma unroll
                for (int j = 8; j < 12; j++) {
                    float w = (i + j < e0) ? __int_as_float(mm[j].y) : 0.f;
                    a0 += w * bf2f(xv[j].x);
                    a1 += w * bf2f(xv[j].y);
                    a2 += w * bf2f(xv[j].z);
                    a3 += w * bf2f(xv[j].w);
                }
            }
            if (g3) {
#pragma unroll
                for (int j = 12; j < 16; j++) {
                    float w = (i + j < e0) ? __int_as_float(mm[j].y) : 0.f;
                    a0 += w * bf2f(xv[j].x);
                    a1 += w * bf2f(xv[j].y);
                    a2 += w * bf2f(xv[j].z);
                    a3 += w * bf2f(xv[j].w);
                }
            }
        }
        ushort4 o;
        o.x = f2bf(a0); o.y = f2bf(a1); o.z = f2bf(a2); o.w = f2bf(a3);
        *(ushort4*)(Y + (wv * 16 + r) * 264 + l * 4) = o;
    }
    __syncthreads();  // Y visible to both waves

    f32x4 acc[2][8] = {};  // [mh][nt]
    int arow = m0 + wv * 16 + l16;  // NN = 625*32 exactly

    auto stageA = [&](int buf, int s) {
        int kt = s * 32;
        const u16* ap;
        int la;
        if (kt < 256) { ap = A0; la = lda0; }
        else          { ap = TX; la = 256; kt -= 256; }
        gll16(ap + (size_t)arow * la + kt + q * 8, lds + buf * 1024 + wv * 512);
    };

    const u16* bfw = Bf + (size_t)(wv * 8) * 512 + l * 8;
    auto loadB = [&](bf16x8* dst, int s) {
#pragma unroll
        for (int j = 0; j < 8; j++)
            dst[j] = *(const bf16x8*)(bfw + (size_t)s * 8192 + j * 512);
    };
    auto comp = [&](int buf, const bf16x8* b) {
        const u16* base = lds + buf * 1024;
        bf16x8 a[2];
#pragma unroll
        for (int mh = 0; mh < 2; mh++)
            a[mh] = *(const bf16x8*)(base + mh * 512 + l * 8);
#pragma unroll
        for (int mh = 0; mh < 2; mh++)
#pragma unroll
            for (int j = 0; j < 8; j++)
                acc[mh][j] =
                    __builtin_amdgcn_mfma_f32_16x16x32_bf16(a[mh], b[j], acc[mh][j], 0, 0, 0);
    };
    auto comp_y = [&](int ss, const bf16x8* b) {
        bf16x8 a[2];
#pragma unroll
        for (int mh = 0; mh < 2; mh++)
            a[mh] = *(const bf16x8*)(Y + (mh * 16 + l16) * 264 + ss * 32 + q * 8);
#pragma unroll
        for (int mh = 0; mh < 2; mh++)
#pragma unroll
            for (int j = 0; j < 8; j++)
                acc[mh][j] =
                    __builtin_amdgcn_mfma_f32_16x16x32_bf16(a[mh], b[j], acc[mh][j], 0, 0, 0);
    };

    bf16x8 bA[8], bB[8];
    // phase A: K=768 = 16 piped steps (x, tx1) + 8 LDS steps (y)
    loadB(bA, 0);
    stageA(0, 0);
    stageA(1, 1);
    stageA(2, 2);
    for (int s = 0; s < 16; s += 2) {
        if (s == 0) asm volatile("s_waitcnt vmcnt(2)" ::: "memory");
        else        asm volatile("s_waitcnt vmcnt(10)" ::: "memory");
        __builtin_amdgcn_s_barrier();
        __builtin_amdgcn_sched_barrier(0);
        loadB(bB, s + 1);
        __builtin_amdgcn_sched_barrier(0);
        if (s + 3 < 16) stageA((s + 3) & 3, s + 3);
        __builtin_amdgcn_sched_barrier(0);
        comp(s & 3, bA);
        asm volatile("s_waitcnt vmcnt(10)" ::: "memory");
        __builtin_amdgcn_s_barrier();
        __builtin_amdgcn_sched_barrier(0);
        loadB(bA, s + 2);  // s+2 <= 16 < 24: always a valid B chunk
        __builtin_amdgcn_sched_barrier(0);
        if (s + 4 < 16) stageA((s + 4) & 3, s + 4);
        __builtin_amdgcn_sched_barrier(0);
        comp((s + 1) & 3, bB);
    }
    // y steps: A from LDS (read-only, barrier'd); B reg deps auto-waited.
    for (int s = 16; s < 24; s += 2) {
        loadB(bB, s + 1);
        comp_y(s - 16, bA);
        if (s + 2 < 24) loadB(bA, s + 2);
        comp_y(s - 15, bB);
    }
    __syncthreads();  // all waves done reading Y / A-bufs; regions reused below

    if (mode == 0) {
        u16* Cs = lds + 4096 + wv * 4352;  // per-wave [32][136] u16 (Y region reuse)
#pragma unroll
        for (int mh = 0; mh < 2; mh++)
#pragma unroll
            for (int j = 0; j < 8; j++)
#pragma unroll
                for (int i = 0; i < 4; i++) {
                    float v = acc[mh][j][i];
                    v = v > 0.f ? v : 0.f;
                    Cs[(mh * 16 + q * 4 + i) * 136 + j * 16 + l16] = f2bf(v);
                }
        // same-wave ds_write->ds_read ordered via lgkmcnt. 512 chunks of 8.
#pragma unroll
        for (int jj = 0; jj < 8; jj++) {
            int f = jj * 64 + l;
            int r = f >> 4, cc = (f & 15) * 8;
            uint4 cv = *(const uint4*)&Cs[r * 136 + cc];
            int row = m0 + r;
            if (row < NN) *(uint4*)(outb + (size_t)row * 1024 + n0 + cc) = cv;
        }
        return;
    }

    // ---- mode 2: fused classifier ----
    // h3 (relu, bf16) -> H3 [32][264]
#pragma unroll
    for (int mh = 0; mh < 2; mh++)
#pragma unroll
        for (int j = 0; j < 8; j++)
#pragma unroll
            for (int i = 0; i < 4; i++) {
                float v = acc[mh][j][i];
                v = v > 0.f ? v : 0.f;
                H3[(mh * 16 + q * 4 + i) * 264 + n0 + j * 16 + l16] = f2bf(v);
            }
    __syncthreads();  // h3 visible to both waves

#pragma unroll
    for (int mh = 0; mh < 2; mh++)
#pragma unroll
        for (int j = 0; j < 8; j++)
            acc[mh][j] = (f32x4){0.f, 0.f, 0.f, 0.f};

    // phase B: z = [jk0,jk1,jk2,h3] @ w1T (K=1024: 24 piped + 8 h3-LDS steps)
    const u16* bfw2 = Bf2 + (size_t)(wv * 8) * 512 + l * 8;
    auto loadB2 = [&](bf16x8* dst, int s) {
#pragma unroll
        for (int j = 0; j < 8; j++)
            dst[j] = *(const bf16x8*)(bfw2 + (size_t)s * 8192 + j * 512);
    };
    auto stageB = [&](int buf, int s) {
        int kt = s * 32;
        const u16* ap = jkb + (size_t)(kt >> 8) * 256;
        gll16(ap + (size_t)arow * 1024 + (kt & 255) + q * 8, lds + buf * 1024 + wv * 512);
    };
    auto comph = [&](int ss, const bf16x8* b) {
        bf16x8 a[2];
#pragma unroll
        for (int mh = 0; mh < 2; mh++)
            a[mh] = *(const bf16x8*)(H3 + (mh * 16 + l16) * 264 + ss * 32 + q * 8);
#pragma unroll
        for (int mh = 0; mh < 2; mh++)
#pragma unroll
            for (int j = 0; j < 8; j++)
                acc[mh][j] =
                    __builtin_amdgcn_mfma_f32_16x16x32_bf16(a[mh], b[j], acc[mh][j], 0, 0, 0);
    };

    loadB2(bA, 0);
    stageB(0, 0);
    stageB(1, 1);
    stageB(2, 2);
    for (int s = 0; s < 24; s += 2) {
        if (s == 0) asm volatile("s_waitcnt vmcnt(2)" ::: "memory");
        else        asm volatile("s_waitcnt vmcnt(10)" ::: "memory");
        __builtin_amdgcn_s_barrier();
        __builtin_amdgcn_sched_barrier(0);
        loadB2(bB, s + 1);
        __builtin_amdgcn_sched_barrier(0);
        if (s + 3 < 24) stageB((s + 3) & 3, s + 3);
        __builtin_amdgcn_sched_barrier(0);
        comp(s & 3, bA);
        asm volatile("s_waitcnt vmcnt(10)" ::: "memory");
        __builtin_amdgcn_s_barrier();
        __builtin_amdgcn_sched_barrier(0);
        loadB2(bA, s + 2);  // s+2 <= 24 < 32: valid chunk
        __builtin_amdgcn_sched_barrier(0);
        if (s + 4 < 24) stageB((s + 4) & 3, s + 4);
        __builtin_amdgcn_sched_barrier(0);
        comp((s + 1) & 3, bB);
    }
    for (int s = 24; s < 32; s += 2) {
        loadB2(bB, s + 1);
        comph(s - 24, bA);
        if (s + 2 < 32) loadB2(bA, s + 2);
        comph(s - 23, bB);
    }

    // classifier epilogue: +b1, relu, BN affine, @w2 + b2 -> logits
    {
        float bi[8], s4[8], h4[8], wa[8], wb[8];
#pragma unroll
        for (int j = 0; j < 8; j++) {
            int col = n0 + j * 16 + l16;
            bi[j] = bias[col];
            s4[j] = sc[col];
            h4[j] = sh[col];
            wa[j] = w2[2 * col];
            wb[j] = w2[2 * col + 1];
        }
        float* red = (float*)lds;  // A-buf area (512 B used)
#pragma unroll
        for (int mh = 0; mh < 2; mh++)
#pragma unroll
            for (int i = 0; i < 4; i++) {
                float p0 = 0.f, p1 = 0.f;
#pragma unroll
                for (int j = 0; j < 8; j++) {
                    float v = acc[mh][j][i] + bi[j];
                    v = v > 0.f ? v : 0.f;
                    v = v * s4[j] + h4[j];
                    p0 += v * wa[j];
                    p1 += v * wb[j];
                }
#pragma unroll
                for (int off = 1; off < 16; off <<= 1) {
                    p0 += __shfl_xor(p0, off, 64);
                    p1 += __shfl_xor(p1, off, 64);
                }
                if (l16 == 0) {
                    int rl = mh * 16 + q * 4 + i;
                    red[(wv * 32 + rl) * 2 + 0] = p0;
                    red[(wv * 32 + rl) * 2 + 1] = p1;
                }
            }
        __syncthreads();
        if (t < 64) {
            int rl = t >> 1, cp = t & 1;
            float v = red[(0 * 32 + rl) * 2 + cp] + red[(1 * 32 + rl) * 2 + cp];
            int row = m0 + rl;
            if (row < NN) outlog[(size_t)row * 2 + cp] = v + b2[cp];
        }
    }
}

extern "C" void kernel_launch(void* const* d_in, const int* in_sizes, int n_in,
                              void* d_out, int out_size, void* d_ws, size_t ws_size,
                              hipStream_t stream) {
    const float* features = (const float*)d_in[0];
    const int* ei = (const int*)d_in[1];
    // d_in[2] = edgenet_input (bypassed by edge_weight_override)
    const float* ew = (const float*)d_in[3];
    const float* cheb_w = (const float*)d_in[4];
    const float* w1 = (const float*)d_in[5];
    const float* b1 = (const float*)d_in[6];
    const float* g = (const float*)d_in[7];
    const float* be = (const float*)d_in[8];
    const float* mn = (const float*)d_in[9];
    const float* vr = (const float*)d_in[10];
    const float* w2 = (const float*)d_in[11];
    const float* b2 = (const float*)d_in[12];
    float* out = (float*)d_out;  // [NN*2] logits, then [EE] ew

    char* p = (char*)d_ws;
    auto alloc = [&](size_t bytes) -> char* {
        char* r = p;
        p += (bytes + 255) & ~(size_t)255;
        return r;
    };
    float* deg = (float*)alloc((size_t)NN * 4);
    int* counts = (int*)alloc((size_t)(NN + 1) * 4);
    int* cursor = (int*)alloc((size_t)NN * 4);
    size_t zero_bytes = (size_t)(p - (char*)deg);
    int* offs = (int*)alloc((size_t)(NN + 1) * 4);
    int2* nbrs = (int2*)alloc((size_t)(EE + 16) * 8);
    u16* xb = (u16*)alloc((size_t)NN * 256 * 2);
    u16* tx1 = (u16*)alloc((size_t)NN * 256 * 2);
    u16* jk = (u16*)alloc((size_t)NN * 1024 * 2);
    u16* chebT = (u16*)alloc((size_t)LGN * 3 * 256 * 256 * 2);  // folded, frag-tiled
    u16* w1T = (u16*)alloc((size_t)1024 * 256 * 2);             // frag-tiled
    float* sc = (float*)alloc(256 * 4);
    float* sh = (float*)alloc(256 * 4);

    hipMemsetAsync(deg, 0, zero_bytes, stream);
    k_edge1<<<(EE + 255) / 256, 256, 0, stream>>>(ei, ew, deg, counts, out + (size_t)NN * 2,
                                                  nbrs);
    k_scan<<<1, 1024, 0, stream>>>(counts, offs);
    k_scatter<<<(EE + 255) / 256, 256, 0, stream>>>(ei, ew, deg, offs, cursor, nbrs);
    const int prep_items = NN * 256 + 4 * 24576 + 32768 + 256;
    k_prep<<<(prep_items + 255) / 256, 256, 0, stream>>>(features, xb, cheb_w, chebT, w1, w1T,
                                                         g, be, mn, vr, sc, sh);

    const int gg = (NN + 31) / 32;  // 625 blocks
    for (int i = 0; i < LGN; i++) {
        const u16* x = (i == 0) ? xb : (jk + (size_t)(i - 1) * 256);
        int ldx = (i == 0) ? 256 : 1024;
        k_prop<<<NN / 4, 256, 0, stream>>>(x, ldx, tx1, offs, nbrs);
        if (i < LGN - 1) {
            k_gemm<<<gg, 128, 0, stream>>>(
                x, ldx, tx1, offs, nbrs, chebT + (size_t)i * 256 * 768,
                (const u16*)nullptr, (const u16*)nullptr, 0, jk + (size_t)i * 256,
                (const float*)nullptr, (const float*)nullptr, (const float*)nullptr,
                (const float*)nullptr, (const float*)nullptr, (float*)nullptr);
        } else {
            k_gemm<<<gg, 128, 0, stream>>>(
                x, ldx, tx1, offs, nbrs, chebT + (size_t)i * 256 * 768,
                w1T, jk, 2, (u16*)nullptr, b1, sc, sh, w2, b2, out);
        }
    }
}

// Round 13
// 433.303 us; speedup vs baseline: 1.1271x; 1.1271x over previous
//
#include <hip/hip_runtime.h>
#include <hip/hip_bf16.h>

#define NN 20000
#define EE 320000
#define LGN 4

typedef unsigned short u16;
typedef short bf16x8 __attribute__((ext_vector_type(8)));
typedef float f32x4 __attribute__((ext_vector_type(4)));

__device__ __forceinline__ float bf2f(u16 v) {
    unsigned int u = ((unsigned int)v) << 16;
    float f; __builtin_memcpy(&f, &u, 4); return f;
}
__device__ __forceinline__ u16 f2bf(float f) {
    __hip_bfloat16 h = __float2bfloat16(f);
    u16 u; __builtin_memcpy(&u, &h, 2); return u;
}

// async global->LDS, 16B per lane, LDS dest = wave-uniform base + lane*16
__device__ __forceinline__ void gll16(const void* g, void* l) {
    __builtin_amdgcn_global_load_lds(
        (const __attribute__((address_space(1))) unsigned int*)g,
        (__attribute__((address_space(3))) unsigned int*)l, 16, 0, 0);
}

// ---- pass 1: degree (by source), col histogram, ew copy-out, pad-zero ----
__global__ __launch_bounds__(256) void k_edge1(const int* __restrict__ ei,
                                               const float* __restrict__ ew,
                                               float* __restrict__ deg,
                                               int* __restrict__ counts,
                                               float* __restrict__ out_ew,
                                               int2* __restrict__ nbrs) {
    int e = blockIdx.x * 256 + threadIdx.x;
    if (blockIdx.x == 0 && threadIdx.x < 16)
        nbrs[EE + threadIdx.x] = make_int2(0, 0);  // gather-overrun pad
    if (e >= EE) return;
    int r = ei[e];
    float w = ew[e];
    atomicAdd(&deg[r], w);
    atomicAdd(&counts[ei[EE + e]], 1);
    out_ew[e] = w;
}

// ---- exclusive scan of col histogram (single block) ----
__global__ __launch_bounds__(1024) void k_scan(const int* __restrict__ counts,
                                               int* __restrict__ offs) {
    __shared__ int part[1024];
    int t = threadIdx.x;
    const int C = (NN + 1023) / 1024;  // 20
    int lo = t * C, hi = min(lo + C, NN);
    int s = 0;
    for (int i = lo; i < hi; i++) s += counts[i];
    part[t] = s;
    __syncthreads();
    for (int off = 1; off < 1024; off <<= 1) {
        int add = (t >= off) ? part[t - off] : 0;
        __syncthreads();
        part[t] += add;
        __syncthreads();
    }
    int base = part[t] - s;
    for (int i = lo; i < hi; i++) { offs[i] = base; base += counts[i]; }
    if (t == 1023) offs[NN] = part[1023];
}

// ---- pass 2: compute norm (rsqrt folded in), scatter into CSR slots ----
__global__ __launch_bounds__(256) void k_scatter(const int* __restrict__ ei,
                                                 const float* __restrict__ ew,
                                                 const float* __restrict__ deg,
                                                 const int* __restrict__ offs,
                                                 int* __restrict__ cursor,
                                                 int2* __restrict__ nbrs) {
    int e = blockIdx.x * 256 + threadIdx.x;
    if (e >= EE) return;
    int r = ei[e], c = ei[EE + e];
    float dr = deg[r], dc = deg[c];
    float ir = (dr > 0.f) ? rsqrtf(dr) : 0.f;
    float ic = (dc > 0.f) ? rsqrtf(dc) : 0.f;
    float nm = -(ir * ew[e] * ic);
    int pidx = offs[c] + atomicAdd(&cursor[c], 1);
    nbrs[pidx] = make_int2(r, __float_as_int(nm));
}

// ---- fragment-tile helpers: one 16B chunk of Bf layout from f32 [K][256] ----
__device__ __forceinline__ void castB_chunk(const float* __restrict__ src,
                                            u16* __restrict__ dst, int u) {
    int l = u & 63, f = (u >> 6) & 15, s = u >> 10;
    int col = f * 16 + (l & 15);
    int kb = s * 32 + ((l >> 4) << 3);
    u16 tmp[8];
#pragma unroll
    for (int j = 0; j < 8; j++) tmp[j] = f2bf(src[(size_t)(kb + j) * 256 + col]);
    *(uint4*)(dst + (size_t)u * 8) = *(uint4*)tmp;
}

// cheb variant with the WEIGHT FOLD (validated in R12 PASS): gemm consumes
// y = L·tx1 raw, so W0' = W0 - W2, W1' = W1, W2' = 2*W2 keeps
// x@W0' + tx1@W1' + y@W2' == x@W0 + tx1@W1 + (2y-x)@W2 exactly (fp32 fold).
__device__ __forceinline__ void castB_chunk_cheb(const float* __restrict__ src,
                                                 u16* __restrict__ dst, int u) {
    int l = u & 63, f = (u >> 6) & 15, s = u >> 10;
    int col = f * 16 + (l & 15);
    int kb = s * 32 + ((l >> 4) << 3);
    u16 tmp[8];
#pragma unroll
    for (int j = 0; j < 8; j++) {
        int k = kb + j;
        float v;
        if (k < 256)       v = src[(size_t)k * 256 + col] - src[(size_t)(k + 512) * 256 + col];
        else if (k < 512)  v = src[(size_t)k * 256 + col];
        else               v = 2.f * src[(size_t)k * 256 + col];
        tmp[j] = f2bf(v);
    }
    *(uint4*)(dst + (size_t)u * 8) = *(uint4*)tmp;
}

// ---- fused prep: features cast + chebT castB x4 (folded) + w1T + foldbn ----
__global__ __launch_bounds__(256) void k_prep(
    const float* __restrict__ features, u16* __restrict__ xb,
    const float* __restrict__ cheb_w, u16* __restrict__ chebT,
    const float* __restrict__ w1, u16* __restrict__ w1T,
    const float* __restrict__ g, const float* __restrict__ be,
    const float* __restrict__ mn, const float* __restrict__ vr,
    float* __restrict__ sc, float* __restrict__ sh) {
    int tid = blockIdx.x * 256 + threadIdx.x;
    if (tid < NN * 256) {
        xb[tid] = f2bf(features[tid]);
        return;
    }
    tid -= NN * 256;
    if (tid < 4 * 24576) {  // chebT: 4 weight sets, K=768 -> 24576 chunks each
        int set = tid / 24576, u = tid - set * 24576;
        castB_chunk_cheb(cheb_w + (size_t)set * 768 * 256, chebT + (size_t)set * 768 * 256, u);
        return;
    }
    tid -= 4 * 24576;
    if (tid < 32768) {  // w1T: K=1024 -> 32768 chunks
        castB_chunk(w1, w1T, tid);
        return;
    }
    tid -= 32768;
    if (tid < 256) {  // fold BN affine
        float s = g[tid] * rsqrtf(vr[tid] + 1e-5f);
        sc[tid] = s;
        sh[tid] = be[tid] - mn[tid] * s;
    }
}

// ---- CSR SpMM: one WAVE per node (R18 ceil-4 form; pure y = L·x) ----
// R22 lesson (R12 regression): the row-gather stream is CONCURRENCY-bound --
// it needs the full 20000-wave TLP of this dedicated dispatch; fusing it
// into the 1250-wave gemm ran it at 1/3 rate. Keep it separate, forever.
__global__ __launch_bounds__(256) void k_prop(const u16* __restrict__ x, int ldx,
                                              u16* __restrict__ out,
                                              const int* __restrict__ offs,
                                              const int2* __restrict__ nbrs) {
    int c = __builtin_amdgcn_readfirstlane(blockIdx.x * 4 + (threadIdx.x >> 6));
    int lane = threadIdx.x & 63;
    int s = offs[c], e = offs[c + 1];
    float a0 = 0.f, a1 = 0.f, a2 = 0.f, a3 = 0.f;
    for (int i = s; i < e; i += 16) {
        int2 mm[16];
        ushort4 xv[16];
        bool g1 = (i + 4 < e), g2 = (i + 8 < e), g3 = (i + 12 < e);  // wave-uniform
#pragma unroll
        for (int j = 0; j < 4; j++) mm[j] = nbrs[i + j];
        if (g1) {
#pragma unroll
            for (int j = 4; j < 8; j++) mm[j] = nbrs[i + j];
        }
        if (g2) {
#pragma unroll
            for (int j = 8; j < 12; j++) mm[j] = nbrs[i + j];
        }
        if (g3) {
#pragma unroll
            for (int j = 12; j < 16; j++) mm[j] = nbrs[i + j];
        }
#pragma unroll
        for (int j = 0; j < 4; j++)
            xv[j] = *(const ushort4*)(x + (size_t)mm[j].x * ldx + lane * 4);
        if (g1) {
#pragma unroll
            for (int j = 4; j < 8; j++)
                xv[j] = *(const ushort4*)(x + (size_t)mm[j].x * ldx + lane * 4);
        }
        if (g2) {
#pragma unroll
            for (int j = 8; j < 12; j++)
                xv[j] = *(const ushort4*)(x + (size_t)mm[j].x * ldx + lane * 4);
        }
        if (g3) {
#pragma unroll
            for (int j = 12; j < 16; j++)
                xv[j] = *(const ushort4*)(x + (size_t)mm[j].x * ldx + lane * 4);
        }
#pragma unroll
        for (int j = 0; j < 4; j++) {
            float w = (i + j < e) ? __int_as_float(mm[j].y) : 0.f;
            a0 += w * bf2f(xv[j].x);
            a1 += w * bf2f(xv[j].y);
            a2 += w * bf2f(xv[j].z);
            a3 += w * bf2f(xv[j].w);
        }
        if (g1) {
#pragma unroll
            for (int j = 4; j < 8; j++) {
                float w = (i + j < e) ? __int_as_float(mm[j].y) : 0.f;
                a0 += w * bf2f(xv[j].x);
                a1 += w * bf2f(xv[j].y);
                a2 += w * bf2f(xv[j].z);
                a3 += w * bf2f(xv[j].w);
            }
        }
        if (g2) {
#pragma unroll
            for (int j = 8; j < 12; j++) {
                float w = (i + j < e) ? __int_as_float(mm[j].y) : 0.f;
                a0 += w * bf2f(xv[j].x);
                a1 += w * bf2f(xv[j].y);
                a2 += w * bf2f(xv[j].z);
                a3 += w * bf2f(xv[j].w);
            }
        }
        if (g3) {
#pragma unroll
            for (int j = 12; j < 16; j++) {
                float w = (i + j < e) ? __int_as_float(mm[j].y) : 0.f;
                a0 += w * bf2f(xv[j].x);
                a1 += w * bf2f(xv[j].y);
                a2 += w * bf2f(xv[j].z);
                a3 += w * bf2f(xv[j].w);
            }
        }
    }
    ushort4 o;
    o.x = f2bf(a0); o.y = f2bf(a1); o.z = f2bf(a2); o.w = f2bf(a3);
    *(ushort4*)(out + (size_t)c * 256 + lane * 4) = o;
}

// ---- bf16 MFMA GEMM, R11-proven form (3 A-inputs, 24 piped steps) ----
// A2 now holds y = L·tx1 (weights folded in chebT). mode 0: relu -> jk
// slice. mode 2: fused layer-3 + classifier (h3 in LDS [32][264], then
// K=1024: jk 0-2 piped + h3 LDS tail, BN/w2 epilogue -> logits).
__global__ __launch_bounds__(128, 2) void k_gemm(
    const u16* __restrict__ A0, const u16* __restrict__ A1,
    const u16* __restrict__ A2,
    int lda0, int lda1, int lda2,
    int K, const u16* __restrict__ Bf, const u16* __restrict__ Bf2,
    const u16* __restrict__ jkb,
    int mode,
    u16* __restrict__ outb, int ldob,
    const float* __restrict__ bias, const float* __restrict__ sc,
    const float* __restrict__ sh,
    const float* __restrict__ w2, const float* __restrict__ b2,
    float* __restrict__ outlog) {
    // [0,4096): 4 A-bufs x 2KB. [4096,12544): h3 [32][264] (mode 2) or
    // mode-0 epilogue Cs (2 waves x 4352 at offset wv*4352, fits 8704).
    __shared__ __align__(16) u16 lds[12544];  // 25088 B
    int t = threadIdx.x;
    int wv = t >> 6, l = t & 63;
    int q = l >> 4, l16 = l & 15;
    int m0 = blockIdx.x * 32;
    int n0 = wv * 128;
    const int steps = K >> 5;  // 24

    f32x4 acc[2][8] = {};  // [mh][nt]

    int arow = m0 + wv * 16 + l16;  // NN = 625*32 exactly; no clamp needed

    auto stageA = [&](int buf, int s) {
        int kt = s * 32;
        int ch = kt >> 8;  // wave-uniform -> SGPR select
        const u16* ap;
        int la;
        if (ch == 0) { ap = A0; la = lda0; }
        else if (ch == 1) { ap = A1; la = lda1; }
        else { ap = A2; la = lda2; }
        gll16(ap + (size_t)arow * la + (kt & 255) + q * 8, lds + buf * 1024 + wv * 512);
    };

    const u16* bfw = Bf + (size_t)(wv * 8) * 512 + l * 8;  // wave frag base + lane
    auto loadB = [&](bf16x8* dst, int s) {
#pragma unroll
        for (int j = 0; j < 8; j++)
            dst[j] = *(const bf16x8*)(bfw + (size_t)s * 8192 + j * 512);
    };
    auto comp = [&](int buf, const bf16x8* b) {
        const u16* base = lds + buf * 1024;
        bf16x8 a[2];
#pragma unroll
        for (int mh = 0; mh < 2; mh++)
            a[mh] = *(const bf16x8*)(base + mh * 512 + l * 8);
#pragma unroll
        for (int mh = 0; mh < 2; mh++)
#pragma unroll
            for (int j = 0; j < 8; j++)
                acc[mh][j] =
                    __builtin_amdgcn_mfma_f32_16x16x32_bf16(a[mh], b[j], acc[mh][j], 0, 0, 0);
    };

    bf16x8 bA[8], bB[8];
    loadB(bA, 0);            // B(0) first: A queue stays behind it
    stageA(0, 0);
    stageA(1, 1);
    stageA(2, 2);
    for (int s = 0; s < steps; s += 2) {
        if (s == 0)               asm volatile("s_waitcnt vmcnt(2)" ::: "memory");
        else                      asm volatile("s_waitcnt vmcnt(10)" ::: "memory");
        __builtin_amdgcn_s_barrier();
        __builtin_amdgcn_sched_barrier(0);
        loadB(bB, s + 1);
        __builtin_amdgcn_sched_barrier(0);
        if (s + 3 < steps) stageA((s + 3) & 3, s + 3);
        __builtin_amdgcn_sched_barrier(0);
        comp(s & 3, bA);
        asm volatile("s_waitcnt vmcnt(10)" ::: "memory");
        __builtin_amdgcn_s_barrier();
        __builtin_amdgcn_sched_barrier(0);
        if (s + 2 < steps) loadB(bA, s + 2);
        __builtin_amdgcn_sched_barrier(0);
        if (s + 4 < steps) stageA((s + 4) & 3, s + 4);
        __builtin_amdgcn_sched_barrier(0);
        comp((s + 1) & 3, bB);
    }
    __syncthreads();  // all waves done with K-loop LDS; reuse below

    if (mode == 0) {
        u16* Cs = lds + 4096 + wv * 4352;  // per-wave [32][136] u16
#pragma unroll
        for (int mh = 0; mh < 2; mh++)
#pragma unroll
            for (int j = 0; j < 8; j++)
#pragma unroll
                for (int i = 0; i < 4; i++) {
                    float v = acc[mh][j][i];
                    v = v > 0.f ? v : 0.f;
                    Cs[(mh * 16 + q * 4 + i) * 136 + j * 16 + l16] = f2bf(v);
                }
        // same-wave ds_write->ds_read ordered via lgkmcnt. 512 chunks of 8.
#pragma unroll
        for (int jj = 0; jj < 8; jj++) {
            int f = jj * 64 + l;
            int r = f >> 4, cc = (f & 15) * 8;
            uint4 cv = *(const uint4*)&Cs[r * 136 + cc];
            int row = m0 + r;
            if (row < NN) *(uint4*)(outb + (size_t)row * ldob + n0 + cc) = cv;
        }
        return;
    }

    // ---- mode 2: fused classifier ----
    // h3 (relu, bf16) -> shared LDS [32][264] row-major
    u16* Csh = lds + 4096;
#pragma unroll
    for (int mh = 0; mh < 2; mh++)
#pragma unroll
        for (int j = 0; j < 8; j++)
#pragma unroll
            for (int i = 0; i < 4; i++) {
                float v = acc[mh][j][i];
                v = v > 0.f ? v : 0.f;
                Csh[(mh * 16 + q * 4 + i) * 264 + n0 + j * 16 + l16] = f2bf(v);
            }
    __syncthreads();  // h3 visible to both waves

#pragma unroll
    for (int mh = 0; mh < 2; mh++)
#pragma unroll
        for (int j = 0; j < 8; j++)
            acc[mh][j] = (f32x4){0.f, 0.f, 0.f, 0.f};

    // phase B: z = [jk0,jk1,jk2,h3] @ w1T (K=1024: 24 piped + 8 h3-LDS steps)
    const u16* bfw2 = Bf2 + (size_t)(wv * 8) * 512 + l * 8;
    auto loadB2 = [&](bf16x8* dst, int s) {
#pragma unroll
        for (int j = 0; j < 8; j++)
            dst[j] = *(const bf16x8*)(bfw2 + (size_t)s * 8192 + j * 512);
    };
    auto stageB = [&](int buf, int s) {
        int kt = s * 32;
        const u16* ap = jkb + (size_t)(kt >> 8) * 256;
        gll16(ap + (size_t)arow * 1024 + (kt & 255) + q * 8, lds + buf * 1024 + wv * 512);
    };
    auto comph = [&](int ss, const bf16x8* b) {
        bf16x8 a[2];
#pragma unroll
        for (int mh = 0; mh < 2; mh++)
            a[mh] = *(const bf16x8*)(Csh + (mh * 16 + l16) * 264 + ss * 32 + q * 8);
#pragma unroll
        for (int mh = 0; mh < 2; mh++)
#pragma unroll
            for (int j = 0; j < 8; j++)
                acc[mh][j] =
                    __builtin_amdgcn_mfma_f32_16x16x32_bf16(a[mh], b[j], acc[mh][j], 0, 0, 0);
    };

    loadB2(bA, 0);
    stageB(0, 0);
    stageB(1, 1);
    stageB(2, 2);
    for (int s = 0; s < 24; s += 2) {
        if (s == 0)               asm volatile("s_waitcnt vmcnt(2)" ::: "memory");
        else                      asm volatile("s_waitcnt vmcnt(10)" ::: "memory");
        __builtin_amdgcn_s_barrier();
        __builtin_amdgcn_sched_barrier(0);
        loadB2(bB, s + 1);
        __builtin_amdgcn_sched_barrier(0);
        if (s + 3 < 24) stageB((s + 3) & 3, s + 3);
        __builtin_amdgcn_sched_barrier(0);
        comp(s & 3, bA);
        asm volatile("s_waitcnt vmcnt(10)" ::: "memory");
        __builtin_amdgcn_s_barrier();
        __builtin_amdgcn_sched_barrier(0);
        loadB2(bA, s + 2);  // s+2 <= 24 < 32 always valid
        __builtin_amdgcn_sched_barrier(0);
        if (s + 4 < 24) stageB((s + 4) & 3, s + 4);
        __builtin_amdgcn_sched_barrier(0);
        comp((s + 1) & 3, bB);
    }
    // h3 steps: no barriers, no manual waits (h3 LDS is read-only now;
    // B regs auto-waited; A-bufs untouched).
    for (int s = 24; s < 32; s += 2) {
        loadB2(bB, s + 1);
        comph(s - 24, bA);
        if (s + 2 < 32) loadB2(bA, s + 2);
        comph(s - 23, bB);
    }

    // classifier epilogue: +b1, relu, BN affine, @w2 + b2 -> logits
    {
        float bi[8], s4[8], h4[8], wa[8], wb[8];
#pragma unroll
        for (int j = 0; j < 8; j++) {
            int col = n0 + j * 16 + l16;
            bi[j] = bias[col];
            s4[j] = sc[col];
            h4[j] = sh[col];
            wa[j] = w2[2 * col];
            wb[j] = w2[2 * col + 1];
        }
        float* red = (float*)lds;  // A-buf area (512 B used)
#pragma unroll
        for (int mh = 0; mh < 2; mh++)
#pragma unroll
            for (int i = 0; i < 4; i++) {
                float p0 = 0.f, p1 = 0.f;
#pragma unroll
                for (int j = 0; j < 8; j++) {
                    float v = acc[mh][j][i] + bi[j];
                    v = v > 0.f ? v : 0.f;
                    v = v * s4[j] + h4[j];
                    p0 += v * wa[j];
                    p1 += v * wb[j];
                }
#pragma unroll
                for (int off = 1; off < 16; off <<= 1) {
                    p0 += __shfl_xor(p0, off, 64);
                    p1 += __shfl_xor(p1, off, 64);
                }
                if (l16 == 0) {
                    int rl = mh * 16 + q * 4 + i;
                    red[(wv * 32 + rl) * 2 + 0] = p0;
                    red[(wv * 32 + rl) * 2 + 1] = p1;
                }
            }
        __syncthreads();
        if (t < 64) {
            int rl = t >> 1, cp = t & 1;
            float v = red[(0 * 32 + rl) * 2 + cp] + red[(1 * 32 + rl) * 2 + cp];
            int row = m0 + rl;
            if (row < NN) outlog[(size_t)row * 2 + cp] = v + b2[cp];
        }
    }
}

extern "C" void kernel_launch(void* const* d_in, const int* in_sizes, int n_in,
                              void* d_out, int out_size, void* d_ws, size_t ws_size,
                              hipStream_t stream) {
    const float* features = (const float*)d_in[0];
    const int* ei = (const int*)d_in[1];
    // d_in[2] = edgenet_input (bypassed by edge_weight_override)
    const float* ew = (const float*)d_in[3];
    const float* cheb_w = (const float*)d_in[4];
    const float* w1 = (const float*)d_in[5];
    const float* b1 = (const float*)d_in[6];
    const float* g = (const float*)d_in[7];
    const float* be = (const float*)d_in[8];
    const float* mn = (const float*)d_in[9];
    const float* vr = (const float*)d_in[10];
    const float* w2 = (const float*)d_in[11];
    const float* b2 = (const float*)d_in[12];
    float* out = (float*)d_out;  // [NN*2] logits, then [EE] ew

    char* p = (char*)d_ws;
    auto alloc = [&](size_t bytes) -> char* {
        char* r = p;
        p += (bytes + 255) & ~(size_t)255;
        return r;
    };
    float* deg = (float*)alloc((size_t)NN * 4);
    int* counts = (int*)alloc((size_t)(NN + 1) * 4);
    int* cursor = (int*)alloc((size_t)NN * 4);
    size_t zero_bytes = (size_t)(p - (char*)deg);
    int* offs = (int*)alloc((size_t)(NN + 1) * 4);
    int2* nbrs = (int2*)alloc((size_t)(EE + 16) * 8);
    u16* xb = (u16*)alloc((size_t)NN * 256 * 2);
    u16* tx1 = (u16*)alloc((size_t)NN * 256 * 2);
    u16* yb = (u16*)alloc((size_t)NN * 256 * 2);   // y = L·tx1 (fold consumes raw)
    u16* jk = (u16*)alloc((size_t)NN * 1024 * 2);
    u16* chebT = (u16*)alloc((size_t)LGN * 3 * 256 * 256 * 2);  // folded, frag-tiled
    u16* w1T = (u16*)alloc((size_t)1024 * 256 * 2);             // frag-tiled
    float* sc = (float*)alloc(256 * 4);
    float* sh = (float*)alloc(256 * 4);

    hipMemsetAsync(deg, 0, zero_bytes, stream);
    k_edge1<<<(EE + 255) / 256, 256, 0, stream>>>(ei, ew, deg, counts, out + (size_t)NN * 2,
                                                  nbrs);
    k_scan<<<1, 1024, 0, stream>>>(counts, offs);
    k_scatter<<<(EE + 255) / 256, 256, 0, stream>>>(ei, ew, deg, offs, cursor, nbrs);
    const int prep_items = NN * 256 + 4 * 24576 + 32768 + 256;
    k_prep<<<(prep_items + 255) / 256, 256, 0, stream>>>(features, xb, cheb_w, chebT, w1, w1T,
                                                         g, be, mn, vr, sc, sh);

    const int gg = (NN + 31) / 32;  // 625 blocks (tile M=32 x N=256, 128 thr)
    for (int i = 0; i < LGN; i++) {
        const u16* x = (i == 0) ? xb : (jk + (size_t)(i - 1) * 256);
        int ldx = (i == 0) ? 256 : 1024;
        k_prop<<<NN / 4, 256, 0, stream>>>(x, ldx, tx1, offs, nbrs);
        k_prop<<<NN / 4, 256, 0, stream>>>(tx1, 256, yb, offs, nbrs);
        if (i < LGN - 1) {
            k_gemm<<<gg, 128, 0, stream>>>(
                x, tx1, yb, ldx, 256, 256, 768, chebT + (size_t)i * 256 * 768,
                (const u16*)nullptr, (const u16*)nullptr, 0, jk + (size_t)i * 256, 1024,
                (const float*)nullptr, (const float*)nullptr, (const float*)nullptr,
                (const float*)nullptr, (const float*)nullptr, (float*)nullptr);
        } else {
            // fused layer-3 cheb gemm + classifier (mode 2)
            k_gemm<<<gg, 128, 0, stream>>>(
                x, tx1, yb, ldx, 256, 256, 768, chebT + (size_t)i * 256 * 768,
                w1T, jk, 2, (u16*)nullptr, 0, b1, sc, sh, w2, b2, out);
        }
    }
}

// Round 14
// 425.460 us; speedup vs baseline: 1.1479x; 1.0184x over previous
//
#include <hip/hip_runtime.h>
#include <hip/hip_bf16.h>

#define NN 20000
#define EE 320000
#define LGN 4

typedef unsigned short u16;
typedef short bf16x8 __attribute__((ext_vector_type(8)));
typedef float f32x4 __attribute__((ext_vector_type(4)));

__device__ __forceinline__ float bf2f(u16 v) {
    unsigned int u = ((unsigned int)v) << 16;
    float f; __builtin_memcpy(&f, &u, 4); return f;
}
__device__ __forceinline__ u16 f2bf(float f) {
    __hip_bfloat16 h = __float2bfloat16(f);
    u16 u; __builtin_memcpy(&u, &h, 2); return u;
}

// async global->LDS, 16B per lane, LDS dest = wave-uniform base + lane*16
__device__ __forceinline__ void gll16(const void* g, void* l) {
    __builtin_amdgcn_global_load_lds(
        (const __attribute__((address_space(1))) unsigned int*)g,
        (__attribute__((address_space(3))) unsigned int*)l, 16, 0, 0);
}

// ---- pass 1: degree (by source), col histogram, ew copy-out, pad-zero ----
__global__ __launch_bounds__(256) void k_edge1(const int* __restrict__ ei,
                                               const float* __restrict__ ew,
                                               float* __restrict__ deg,
                                               int* __restrict__ counts,
                                               float* __restrict__ out_ew,
                                               int2* __restrict__ nbrs) {
    int e = blockIdx.x * 256 + threadIdx.x;
    if (blockIdx.x == 0 && threadIdx.x < 16)
        nbrs[EE + threadIdx.x] = make_int2(0, 0);  // gather-overrun pad
    if (e >= EE) return;
    int r = ei[e];
    float w = ew[e];
    atomicAdd(&deg[r], w);
    atomicAdd(&counts[ei[EE + e]], 1);
    out_ew[e] = w;
}

// ---- exclusive scan of col histogram (single block) ----
__global__ __launch_bounds__(1024) void k_scan(const int* __restrict__ counts,
                                               int* __restrict__ offs) {
    __shared__ int part[1024];
    int t = threadIdx.x;
    const int C = (NN + 1023) / 1024;  // 20
    int lo = t * C, hi = min(lo + C, NN);
    int s = 0;
    for (int i = lo; i < hi; i++) s += counts[i];
    part[t] = s;
    __syncthreads();
    for (int off = 1; off < 1024; off <<= 1) {
        int add = (t >= off) ? part[t - off] : 0;
        __syncthreads();
        part[t] += add;
        __syncthreads();
    }
    int base = part[t] - s;
    for (int i = lo; i < hi; i++) { offs[i] = base; base += counts[i]; }
    if (t == 1023) offs[NN] = part[1023];
}

// ---- pass 2: compute norm (rsqrt folded in), scatter into CSR slots ----
__global__ __launch_bounds__(256) void k_scatter(const int* __restrict__ ei,
                                                 const float* __restrict__ ew,
                                                 const float* __restrict__ deg,
                                                 const int* __restrict__ offs,
                                                 int* __restrict__ cursor,
                                                 int2* __restrict__ nbrs) {
    int e = blockIdx.x * 256 + threadIdx.x;
    if (e >= EE) return;
    int r = ei[e], c = ei[EE + e];
    float dr = deg[r], dc = deg[c];
    float ir = (dr > 0.f) ? rsqrtf(dr) : 0.f;
    float ic = (dc > 0.f) ? rsqrtf(dc) : 0.f;
    float nm = -(ir * ew[e] * ic);
    int pidx = offs[c] + atomicAdd(&cursor[c], 1);
    nbrs[pidx] = make_int2(r, __float_as_int(nm));
}

// ---- fragment-tile helpers: one 16B chunk of Bf layout from f32 [K][256] ----
__device__ __forceinline__ void castB_chunk(const float* __restrict__ src,
                                            u16* __restrict__ dst, int u) {
    int l = u & 63, f = (u >> 6) & 15, s = u >> 10;
    int col = f * 16 + (l & 15);
    int kb = s * 32 + ((l >> 4) << 3);
    u16 tmp[8];
#pragma unroll
    for (int j = 0; j < 8; j++) tmp[j] = f2bf(src[(size_t)(kb + j) * 256 + col]);
    *(uint4*)(dst + (size_t)u * 8) = *(uint4*)tmp;
}

// cheb variant with the WEIGHT FOLD (validated R12/R13): gemm consumes
// y = L·tx1 raw, so W0' = W0 - W2, W1' = W1, W2' = 2*W2 keeps
// x@W0' + tx1@W1' + y@W2' == x@W0 + tx1@W1 + (2y-x)@W2 exactly (fp32 fold).
__device__ __forceinline__ void castB_chunk_cheb(const float* __restrict__ src,
                                                 u16* __restrict__ dst, int u) {
    int l = u & 63, f = (u >> 6) & 15, s = u >> 10;
    int col = f * 16 + (l & 15);
    int kb = s * 32 + ((l >> 4) << 3);
    u16 tmp[8];
#pragma unroll
    for (int j = 0; j < 8; j++) {
        int k = kb + j;
        float v;
        if (k < 256)       v = src[(size_t)k * 256 + col] - src[(size_t)(k + 512) * 256 + col];
        else if (k < 512)  v = src[(size_t)k * 256 + col];
        else               v = 2.f * src[(size_t)k * 256 + col];
        tmp[j] = f2bf(v);
    }
    *(uint4*)(dst + (size_t)u * 8) = *(uint4*)tmp;
}

// ---- fused prep: features cast + chebT castB x4 (folded) + w1T + foldbn ----
__global__ __launch_bounds__(256) void k_prep(
    const float* __restrict__ features, u16* __restrict__ xb,
    const float* __restrict__ cheb_w, u16* __restrict__ chebT,
    const float* __restrict__ w1, u16* __restrict__ w1T,
    const float* __restrict__ g, const float* __restrict__ be,
    const float* __restrict__ mn, const float* __restrict__ vr,
    float* __restrict__ sc, float* __restrict__ sh) {
    int tid = blockIdx.x * 256 + threadIdx.x;
    if (tid < NN * 256) {
        xb[tid] = f2bf(features[tid]);
        return;
    }
    tid -= NN * 256;
    if (tid < 4 * 24576) {  // chebT: 4 weight sets, K=768 -> 24576 chunks each
        int set = tid / 24576, u = tid - set * 24576;
        castB_chunk_cheb(cheb_w + (size_t)set * 768 * 256, chebT + (size_t)set * 768 * 256, u);
        return;
    }
    tid -= 4 * 24576;
    if (tid < 32768) {  // w1T: K=1024 -> 32768 chunks
        castB_chunk(w1, w1T, tid);
        return;
    }
    tid -= 32768;
    if (tid < 256) {  // fold BN affine
        float s = g[tid] * rsqrtf(vr[tid] + 1e-5f);
        sc[tid] = s;
        sh[tid] = be[tid] - mn[tid] * s;
    }
}

// ---- CSR SpMM: one WAVE per node (R18 ceil-4 form; pure y = L·x) ----
// R22 lesson: the row-gather stream is CONCURRENCY-bound -- needs the full
// 20000-wave TLP of this dedicated dispatch. Keep separate.
__global__ __launch_bounds__(256) void k_prop(const u16* __restrict__ x, int ldx,
                                              u16* __restrict__ out,
                                              const int* __restrict__ offs,
                                              const int2* __restrict__ nbrs) {
    int c = __builtin_amdgcn_readfirstlane(blockIdx.x * 4 + (threadIdx.x >> 6));
    int lane = threadIdx.x & 63;
    int s = offs[c], e = offs[c + 1];
    float a0 = 0.f, a1 = 0.f, a2 = 0.f, a3 = 0.f;
    for (int i = s; i < e; i += 16) {
        int2 mm[16];
        ushort4 xv[16];
        bool g1 = (i + 4 < e), g2 = (i + 8 < e), g3 = (i + 12 < e);  // wave-uniform
#pragma unroll
        for (int j = 0; j < 4; j++) mm[j] = nbrs[i + j];
        if (g1) {
#pragma unroll
            for (int j = 4; j < 8; j++) mm[j] = nbrs[i + j];
        }
        if (g2) {
#pragma unroll
            for (int j = 8; j < 12; j++) mm[j] = nbrs[i + j];
        }
        if (g3) {
#pragma unroll
            for (int j = 12; j < 16; j++) mm[j] = nbrs[i + j];
        }
#pragma unroll
        for (int j = 0; j < 4; j++)
            xv[j] = *(const ushort4*)(x + (size_t)mm[j].x * ldx + lane * 4);
        if (g1) {
#pragma unroll
            for (int j = 4; j < 8; j++)
                xv[j] = *(const ushort4*)(x + (size_t)mm[j].x * ldx + lane * 4);
        }
        if (g2) {
#pragma unroll
            for (int j = 8; j < 12; j++)
                xv[j] = *(const ushort4*)(x + (size_t)mm[j].x * ldx + lane * 4);
        }
        if (g3) {
#pragma unroll
            for (int j = 12; j < 16; j++)
                xv[j] = *(const ushort4*)(x + (size_t)mm[j].x * ldx + lane * 4);
        }
#pragma unroll
        for (int j = 0; j < 4; j++) {
            float w = (i + j < e) ? __int_as_float(mm[j].y) : 0.f;
            a0 += w * bf2f(xv[j].x);
            a1 += w * bf2f(xv[j].y);
            a2 += w * bf2f(xv[j].z);
            a3 += w * bf2f(xv[j].w);
        }
        if (g1) {
#pragma unroll
            for (int j = 4; j < 8; j++) {
                float w = (i + j < e) ? __int_as_float(mm[j].y) : 0.f;
                a0 += w * bf2f(xv[j].x);
                a1 += w * bf2f(xv[j].y);
                a2 += w * bf2f(xv[j].z);
                a3 += w * bf2f(xv[j].w);
            }
        }
        if (g2) {
#pragma unroll
            for (int j = 8; j < 12; j++) {
                float w = (i + j < e) ? __int_as_float(mm[j].y) : 0.f;
                a0 += w * bf2f(xv[j].x);
                a1 += w * bf2f(xv[j].y);
                a2 += w * bf2f(xv[j].z);
                a3 += w * bf2f(xv[j].w);
            }
        }
        if (g3) {
#pragma unroll
            for (int j = 12; j < 16; j++) {
                float w = (i + j < e) ? __int_as_float(mm[j].y) : 0.f;
                a0 += w * bf2f(xv[j].x);
                a1 += w * bf2f(xv[j].y);
                a2 += w * bf2f(xv[j].z);
                a3 += w * bf2f(xv[j].w);
            }
        }
    }
    ushort4 o;
    o.x = f2bf(a0); o.y = f2bf(a1); o.z = f2bf(a2); o.w = f2bf(a3);
    *(ushort4*)(out + (size_t)c * 256 + lane * 4) = o;
}

// ---- R24 MFMA GEMM: tile M=32 x N=256, 4 WAVES (256 thr) ----
// Occupancy probe: 128-thr blocks gave only ~4.9 waves/CU during gemm (no
// TLP to hide B L2 loads). Now wave wv owns cols wv*64..+63 (4 b-frags, 8
// MFMA/step); waves 0-1 stage the two A-frags (per-half issue: 4 B + 1 A).
// Head waits exact: even0 vmcnt(2) [B0*4,A0,A1,A2 -> retire 5], odd0
// vmcnt(6) [A1,A2,B1*4,A3 -> retire A1], steady vmcnt(10). Safety anchor:
// comp(s-1)'s implicit B(s-1)-reg wait retires A(s) (issued before B(s-1)
// in FIFO) before the iter-s barrier. Waves 2-3 issue no DMA; their waits
// are no-ops and the barrier delivers A-data.
// mode 0: relu -> jk slice (per-wave [32][72] LDS transpose, 64-col slice).
// mode 2: fused layer-3 + classifier (4-slice h3 [32][264], K=1024 = 24
// piped jk steps + 8 h3-LDS steps, 4-wave reduce epilogue).
__global__ __launch_bounds__(256, 2) void k_gemm(
    const u16* __restrict__ A0, const u16* __restrict__ A1,
    const u16* __restrict__ A2,
    int lda0, int lda1, int lda2,
    int K, const u16* __restrict__ Bf, const u16* __restrict__ Bf2,
    const u16* __restrict__ jkb,
    int mode,
    u16* __restrict__ outb, int ldob,
    const float* __restrict__ bias, const float* __restrict__ sc,
    const float* __restrict__ sh,
    const float* __restrict__ w2, const float* __restrict__ b2,
    float* __restrict__ outlog) {
    // u16 units: A-bufs [0,4096) 4 x 2KB. mode0: Cs 4 waves x [32][72]
    // at [4096, 4096+9216). mode2: H3 [32][264] at [4096, 12544).
    __shared__ __align__(16) u16 lds[13312];  // 26624 B
    int t = threadIdx.x;
    int wv = t >> 6, l = t & 63;
    int q = l >> 4, l16 = l & 15;
    int m0 = blockIdx.x * 32;
    int n0 = wv * 64;
    const int steps = K >> 5;  // 24

    f32x4 acc[2][4] = {};  // [mh][nt]

    int arow = m0 + min(wv, 1) * 16 + l16;  // staging rows (waves 0-1 only)

    auto stageA = [&](int buf, int s) {
        if (wv >= 2) return;
        int kt = s * 32;
        int ch = kt >> 8;  // wave-uniform -> SGPR select
        const u16* ap;
        int la;
        if (ch == 0) { ap = A0; la = lda0; }
        else if (ch == 1) { ap = A1; la = lda1; }
        else { ap = A2; la = lda2; }
        gll16(ap + (size_t)arow * la + (kt & 255) + q * 8, lds + buf * 1024 + wv * 512);
    };

    const u16* bfw = Bf + (size_t)(wv * 4) * 512 + l * 8;  // wave frag base + lane
    auto loadB = [&](bf16x8* dst, int s) {
#pragma unroll
        for (int j = 0; j < 4; j++)
            dst[j] = *(const bf16x8*)(bfw + (size_t)s * 8192 + j * 512);
    };
    auto comp = [&](int buf, const bf16x8* b) {
        const u16* base = lds + buf * 1024;
        bf16x8 a[2];
#pragma unroll
        for (int mh = 0; mh < 2; mh++)
            a[mh] = *(const bf16x8*)(base + mh * 512 + l * 8);
#pragma unroll
        for (int mh = 0; mh < 2; mh++)
#pragma unroll
            for (int j = 0; j < 4; j++)
                acc[mh][j] =
                    __builtin_amdgcn_mfma_f32_16x16x32_bf16(a[mh], b[j], acc[mh][j], 0, 0, 0);
    };

    bf16x8 bA[4], bB[4];
    loadB(bA, 0);            // B(0) first: A queue stays behind it
    stageA(0, 0);
    stageA(1, 1);
    stageA(2, 2);
    for (int s = 0; s < steps; s += 2) {
        if (s == 0)               asm volatile("s_waitcnt vmcnt(2)" ::: "memory");
        else                      asm volatile("s_waitcnt vmcnt(10)" ::: "memory");
        __builtin_amdgcn_s_barrier();
        __builtin_amdgcn_sched_barrier(0);
        loadB(bB, s + 1);
        __builtin_amdgcn_sched_barrier(0);
        if (s + 3 < steps) stageA((s + 3) & 3, s + 3);
        __builtin_amdgcn_sched_barrier(0);
        comp(s & 3, bA);
        if (s == 0)               asm volatile("s_waitcnt vmcnt(6)" ::: "memory");
        else                      asm volatile("s_waitcnt vmcnt(10)" ::: "memory");
        __builtin_amdgcn_s_barrier();
        __builtin_amdgcn_sched_barrier(0);
        if (s + 2 < steps) loadB(bA, s + 2);
        __builtin_amdgcn_sched_barrier(0);
        if (s + 4 < steps) stageA((s + 4) & 3, s + 4);
        __builtin_amdgcn_sched_barrier(0);
        comp((s + 1) & 3, bB);
    }
    __syncthreads();  // all waves done with K-loop LDS; reuse below

    if (mode == 0) {
        u16* Cs = lds + 4096 + wv * 2304;  // per-wave [32][72] u16
#pragma unroll
        for (int mh = 0; mh < 2; mh++)
#pragma unroll
            for (int j = 0; j < 4; j++)
#pragma unroll
                for (int i = 0; i < 4; i++) {
                    float v = acc[mh][j][i];
                    v = v > 0.f ? v : 0.f;
                    Cs[(mh * 16 + q * 4 + i) * 72 + j * 16 + l16] = f2bf(v);
                }
        // same-wave ds_write->ds_read ordered via lgkmcnt. 32x64 = 256 chunks.
#pragma unroll
        for (int jj = 0; jj < 4; jj++) {
            int f = jj * 64 + l;
            int r = f >> 3, cc = (f & 7) * 8;
            uint4 cv = *(const uint4*)&Cs[r * 72 + cc];
            int row = m0 + r;
            if (row < NN) *(uint4*)(outb + (size_t)row * ldob + n0 + cc) = cv;
        }
        return;
    }

    // ---- mode 2: fused classifier ----
    // h3 (relu, bf16) -> shared LDS [32][264]; wave wv writes its 64-col slice
    u16* Csh = lds + 4096;
#pragma unroll
    for (int mh = 0; mh < 2; mh++)
#pragma unroll
        for (int j = 0; j < 4; j++)
#pragma unroll
            for (int i = 0; i < 4; i++) {
                float v = acc[mh][j][i];
                v = v > 0.f ? v : 0.f;
                Csh[(mh * 16 + q * 4 + i) * 264 + n0 + j * 16 + l16] = f2bf(v);
            }
    __syncthreads();  // h3 visible to all waves

#pragma unroll
    for (int mh = 0; mh < 2; mh++)
#pragma unroll
        for (int j = 0; j < 4; j++)
            acc[mh][j] = (f32x4){0.f, 0.f, 0.f, 0.f};

    // phase B: z = [jk0,jk1,jk2,h3] @ w1T (K=1024: 24 piped + 8 h3-LDS steps)
    const u16* bfw2 = Bf2 + (size_t)(wv * 4) * 512 + l * 8;
    auto loadB2 = [&](bf16x8* dst, int s) {
#pragma unroll
        for (int j = 0; j < 4; j++)
            dst[j] = *(const bf16x8*)(bfw2 + (size_t)s * 8192 + j * 512);
    };
    auto stageB = [&](int buf, int s) {
        if (wv >= 2) return;
        int kt = s * 32;
        const u16* ap = jkb + (size_t)(kt >> 8) * 256;
        gll16(ap + (size_t)arow * 1024 + (kt & 255) + q * 8, lds + buf * 1024 + wv * 512);
    };
    auto comph = [&](int ss, const bf16x8* b) {
        bf16x8 a[2];
#pragma unroll
        for (int mh = 0; mh < 2; mh++)
            a[mh] = *(const bf16x8*)(Csh + (mh * 16 + l16) * 264 + ss * 32 + q * 8);
#pragma unroll
        for (int mh = 0; mh < 2; mh++)
#pragma unroll
            for (int j = 0; j < 4; j++)
                acc[mh][j] =
                    __builtin_amdgcn_mfma_f32_16x16x32_bf16(a[mh], b[j], acc[mh][j], 0, 0, 0);
    };

    loadB2(bA, 0);
    stageB(0, 0);
    stageB(1, 1);
    stageB(2, 2);
    for (int s = 0; s < 24; s += 2) {
        if (s == 0)               asm volatile("s_waitcnt vmcnt(2)" ::: "memory");
        else                      asm volatile("s_waitcnt vmcnt(10)" ::: "memory");
        __builtin_amdgcn_s_barrier();
        __builtin_amdgcn_sched_barrier(0);
        loadB2(bB, s + 1);
        __builtin_amdgcn_sched_barrier(0);
        if (s + 3 < 24) stageB((s + 3) & 3, s + 3);
        __builtin_amdgcn_sched_barrier(0);
        comp(s & 3, bA);
        if (s == 0)               asm volatile("s_waitcnt vmcnt(6)" ::: "memory");
        else                      asm volatile("s_waitcnt vmcnt(10)" ::: "memory");
        __builtin_amdgcn_s_barrier();
        __builtin_amdgcn_sched_barrier(0);
        loadB2(bA, s + 2);  // s+2 <= 24 < 32 always valid
        __builtin_amdgcn_sched_barrier(0);
        if (s + 4 < 24) stageB((s + 4) & 3, s + 4);
        __builtin_amdgcn_sched_barrier(0);
        comp((s + 1) & 3, bB);
    }
    // h3 steps: no barriers, no manual waits (h3 LDS read-only; B regs
    // auto-waited; A-bufs untouched).
    for (int s = 24; s < 32; s += 2) {
        loadB2(bB, s + 1);
        comph(s - 24, bA);
        if (s + 2 < 32) loadB2(bA, s + 2);
        comph(s - 23, bB);
    }

    // classifier epilogue: +b1, relu, BN affine, @w2 + b2 -> logits
    {
        float bi[4], s4[4], h4[4], wa[4], wb[4];
#pragma unroll
        for (int j = 0; j < 4; j++) {
            int col = n0 + j * 16 + l16;
            bi[j] = bias[col];
            s4[j] = sc[col];
            h4[j] = sh[col];
            wa[j] = w2[2 * col];
            wb[j] = w2[2 * col + 1];
        }
        float* red = (float*)lds;  // A-buf area: [4 waves][32 rows][2] floats
#pragma unroll
        for (int mh = 0; mh < 2; mh++)
#pragma unroll
            for (int i = 0; i < 4; i++) {
                float p0 = 0.f, p1 = 0.f;
#pragma unroll
                for (int j = 0; j < 4; j++) {
                    float v = acc[mh][j][i] + bi[j];
                    v = v > 0.f ? v : 0.f;
                    v = v * s4[j] + h4[j];
                    p0 += v * wa[j];
                    p1 += v * wb[j];
                }
#pragma unroll
                for (int off = 1; off < 16; off <<= 1) {
                    p0 += __shfl_xor(p0, off, 64);
                    p1 += __shfl_xor(p1, off, 64);
                }
                if (l16 == 0) {
                    int rl = mh * 16 + q * 4 + i;
                    red[(wv * 32 + rl) * 2 + 0] = p0;
                    red[(wv * 32 + rl) * 2 + 1] = p1;
                }
            }
        __syncthreads();
        if (t < 64) {
            int rl = t >> 1, cp = t & 1;
            float v = red[(0 * 32 + rl) * 2 + cp] + red[(1 * 32 + rl) * 2 + cp] +
                      red[(2 * 32 + rl) * 2 + cp] + red[(3 * 32 + rl) * 2 + cp];
            int row = m0 + rl;
            if (row < NN) outlog[(size_t)row * 2 + cp] = v + b2[cp];
        }
    }
}

extern "C" void kernel_launch(void* const* d_in, const int* in_sizes, int n_in,
                              void* d_out, int out_size, void* d_ws, size_t ws_size,
                              hipStream_t stream) {
    const float* features = (const float*)d_in[0];
    const int* ei = (const int*)d_in[1];
    // d_in[2] = edgenet_input (bypassed by edge_weight_override)
    const float* ew = (const float*)d_in[3];
    const float* cheb_w = (const float*)d_in[4];
    const float* w1 = (const float*)d_in[5];
    const float* b1 = (const float*)d_in[6];
    const float* g = (const float*)d_in[7];
    const float* be = (const float*)d_in[8];
    const float* mn = (const float*)d_in[9];
    const float* vr = (const float*)d_in[10];
    const float* w2 = (const float*)d_in[11];
    const float* b2 = (const float*)d_in[12];
    float* out = (float*)d_out;  // [NN*2] logits, then [EE] ew

    char* p = (char*)d_ws;
    auto alloc = [&](size_t bytes) -> char* {
        char* r = p;
        p += (bytes + 255) & ~(size_t)255;
        return r;
    };
    float* deg = (float*)alloc((size_t)NN * 4);
    int* counts = (int*)alloc((size_t)(NN + 1) * 4);
    int* cursor = (int*)alloc((size_t)NN * 4);
    size_t zero_bytes = (size_t)(p - (char*)deg);
    int* offs = (int*)alloc((size_t)(NN + 1) * 4);
    int2* nbrs = (int2*)alloc((size_t)(EE + 16) * 8);
    u16* xb = (u16*)alloc((size_t)NN * 256 * 2);
    u16* tx1 = (u16*)alloc((size_t)NN * 256 * 2);
    u16* yb = (u16*)alloc((size_t)NN * 256 * 2);   // y = L·tx1 (fold consumes raw)
    u16* jk = (u16*)alloc((size_t)NN * 1024 * 2);
    u16* chebT = (u16*)alloc((size_t)LGN * 3 * 256 * 256 * 2);  // folded, frag-tiled
    u16* w1T = (u16*)alloc((size_t)1024 * 256 * 2);             // frag-tiled
    float* sc = (float*)alloc(256 * 4);
    float* sh = (float*)alloc(256 * 4);

    hipMemsetAsync(deg, 0, zero_bytes, stream);
    k_edge1<<<(EE + 255) / 256, 256, 0, stream>>>(ei, ew, deg, counts, out + (size_t)NN * 2,
                                                  nbrs);
    k_scan<<<1, 1024, 0, stream>>>(counts, offs);
    k_scatter<<<(EE + 255) / 256, 256, 0, stream>>>(ei, ew, deg, offs, cursor, nbrs);
    const int prep_items = NN * 256 + 4 * 24576 + 32768 + 256;
    k_prep<<<(prep_items + 255) / 256, 256, 0, stream>>>(features, xb, cheb_w, chebT, w1, w1T,
                                                         g, be, mn, vr, sc, sh);

    const int gg = (NN + 31) / 32;  // 625 blocks (tile M=32 x N=256, 256 thr)
    for (int i = 0; i < LGN; i++) {
        const u16* x = (i == 0) ? xb : (jk + (size_t)(i - 1) * 256);
        int ldx = (i == 0) ? 256 : 1024;
        k_prop<<<NN / 4, 256, 0, stream>>>(x, ldx, tx1, offs, nbrs);
        k_prop<<<NN / 4, 256, 0, stream>>>(tx1, 256, yb, offs, nbrs);
        if (i < LGN - 1) {
            k_gemm<<<gg, 256, 0, stream>>>(
                x, tx1, yb, ldx, 256, 256, 768, chebT + (size_t)i * 256 * 768,
                (const u16*)nullptr, (const u16*)nullptr, 0, jk + (size_t)i * 256, 1024,
                (const float*)nullptr, (const float*)nullptr, (const float*)nullptr,
                (const float*)nullptr, (const float*)nullptr, (float*)nullptr);
        } else {
            // fused layer-3 cheb gemm + classifier (mode 2)
            k_gemm<<<gg, 256, 0, stream>>>(
                x, tx1, yb, ldx, 256, 256, 768, chebT + (size_t)i * 256 * 768,
                w1T, jk, 2, (u16*)nullptr, 0, b1, sc, sh, w2, b2, out);
        }
    }
}

// Round 15
// 425.052 us; speedup vs baseline: 1.1490x; 1.0010x over previous
//
#include <hip/hip_runtime.h>
#include <hip/hip_bf16.h>

#define NN 20000
#define EE 320000
#define LGN 4

typedef unsigned short u16;
typedef short bf16x8 __attribute__((ext_vector_type(8)));
typedef float f32x4 __attribute__((ext_vector_type(4)));

__device__ __forceinline__ float bf2f(u16 v) {
    unsigned int u = ((unsigned int)v) << 16;
    float f; __builtin_memcpy(&f, &u, 4); return f;
}
__device__ __forceinline__ u16 f2bf(float f) {
    __hip_bfloat16 h = __float2bfloat16(f);
    u16 u; __builtin_memcpy(&u, &h, 2); return u;
}

// async global->LDS, 16B per lane, LDS dest = wave-uniform base + lane*16
__device__ __forceinline__ void gll16(const void* g, void* l) {
    __builtin_amdgcn_global_load_lds(
        (const __attribute__((address_space(1))) unsigned int*)g,
        (__attribute__((address_space(3))) unsigned int*)l, 16, 0, 0);
}

// ---- pass 1: degree (by source), col histogram, ew copy-out, pad-zero ----
__global__ __launch_bounds__(256) void k_edge1(const int* __restrict__ ei,
                                               const float* __restrict__ ew,
                                               float* __restrict__ deg,
                                               int* __restrict__ counts,
                                               float* __restrict__ out_ew,
                                               int2* __restrict__ nbrs) {
    int e = blockIdx.x * 256 + threadIdx.x;
    if (blockIdx.x == 0 && threadIdx.x < 16)
        nbrs[EE + threadIdx.x] = make_int2(0, 0);  // gather-overrun pad
    if (e >= EE) return;
    int r = ei[e];
    float w = ew[e];
    atomicAdd(&deg[r], w);
    atomicAdd(&counts[ei[EE + e]], 1);
    out_ew[e] = w;
}

// ---- exclusive scan of col histogram (single block) ----
__global__ __launch_bounds__(1024) void k_scan(const int* __restrict__ counts,
                                               int* __restrict__ offs) {
    __shared__ int part[1024];
    int t = threadIdx.x;
    const int C = (NN + 1023) / 1024;  // 20
    int lo = t * C, hi = min(lo + C, NN);
    int s = 0;
    for (int i = lo; i < hi; i++) s += counts[i];
    part[t] = s;
    __syncthreads();
    for (int off = 1; off < 1024; off <<= 1) {
        int add = (t >= off) ? part[t - off] : 0;
        __syncthreads();
        part[t] += add;
        __syncthreads();
    }
    int base = part[t] - s;
    for (int i = lo; i < hi; i++) { offs[i] = base; base += counts[i]; }
    if (t == 1023) offs[NN] = part[1023];
}

// ---- pass 2: compute norm (rsqrt folded in), scatter into CSR slots ----
__global__ __launch_bounds__(256) void k_scatter(const int* __restrict__ ei,
                                                 const float* __restrict__ ew,
                                                 const float* __restrict__ deg,
                                                 const int* __restrict__ offs,
                                                 int* __restrict__ cursor,
                                                 int2* __restrict__ nbrs) {
    int e = blockIdx.x * 256 + threadIdx.x;
    if (e >= EE) return;
    int r = ei[e], c = ei[EE + e];
    float dr = deg[r], dc = deg[c];
    float ir = (dr > 0.f) ? rsqrtf(dr) : 0.f;
    float ic = (dc > 0.f) ? rsqrtf(dc) : 0.f;
    float nm = -(ir * ew[e] * ic);
    int pidx = offs[c] + atomicAdd(&cursor[c], 1);
    nbrs[pidx] = make_int2(r, __float_as_int(nm));
}

// ---- fragment-tile helpers: one 16B chunk of Bf layout from f32 [K][256] ----
__device__ __forceinline__ void castB_chunk(const float* __restrict__ src,
                                            u16* __restrict__ dst, int u) {
    int l = u & 63, f = (u >> 6) & 15, s = u >> 10;
    int col = f * 16 + (l & 15);
    int kb = s * 32 + ((l >> 4) << 3);
    u16 tmp[8];
#pragma unroll
    for (int j = 0; j < 8; j++) tmp[j] = f2bf(src[(size_t)(kb + j) * 256 + col]);
    *(uint4*)(dst + (size_t)u * 8) = *(uint4*)tmp;
}

// cheb variant with the WEIGHT FOLD (validated R12/R13): gemm consumes
// y = L·tx1 raw, so W0' = W0 - W2, W1' = W1, W2' = 2*W2 keeps
// x@W0' + tx1@W1' + y@W2' == x@W0 + tx1@W1 + (2y-x)@W2 exactly (fp32 fold).
__device__ __forceinline__ void castB_chunk_cheb(const float* __restrict__ src,
                                                 u16* __restrict__ dst, int u) {
    int l = u & 63, f = (u >> 6) & 15, s = u >> 10;
    int col = f * 16 + (l & 15);
    int kb = s * 32 + ((l >> 4) << 3);
    u16 tmp[8];
#pragma unroll
    for (int j = 0; j < 8; j++) {
        int k = kb + j;
        float v;
        if (k < 256)       v = src[(size_t)k * 256 + col] - src[(size_t)(k + 512) * 256 + col];
        else if (k < 512)  v = src[(size_t)k * 256 + col];
        else               v = 2.f * src[(size_t)k * 256 + col];
        tmp[j] = f2bf(v);
    }
    *(uint4*)(dst + (size_t)u * 8) = *(uint4*)tmp;
}

// ---- fused prep: features cast + chebT castB x4 (folded) + w1T + foldbn ----
__global__ __launch_bounds__(256) void k_prep(
    const float* __restrict__ features, u16* __restrict__ xb,
    const float* __restrict__ cheb_w, u16* __restrict__ chebT,
    const float* __restrict__ w1, u16* __restrict__ w1T,
    const float* __restrict__ g, const float* __restrict__ be,
    const float* __restrict__ mn, const float* __restrict__ vr,
    float* __restrict__ sc, float* __restrict__ sh) {
    int tid = blockIdx.x * 256 + threadIdx.x;
    if (tid < NN * 256) {
        xb[tid] = f2bf(features[tid]);
        return;
    }
    tid -= NN * 256;
    if (tid < 4 * 24576) {  // chebT: 4 weight sets, K=768 -> 24576 chunks each
        int set = tid / 24576, u = tid - set * 24576;
        castB_chunk_cheb(cheb_w + (size_t)set * 768 * 256, chebT + (size_t)set * 768 * 256, u);
        return;
    }
    tid -= 4 * 24576;
    if (tid < 32768) {  // w1T: K=1024 -> 32768 chunks
        castB_chunk(w1, w1T, tid);
        return;
    }
    tid -= 32768;
    if (tid < 256) {  // fold BN affine
        float s = g[tid] * rsqrtf(vr[tid] + 1e-5f);
        sc[tid] = s;
        sh[tid] = be[tid] - mn[tid] * s;
    }
}

// ---- CSR SpMM: one WAVE per node (R18 ceil-4 form; pure y = L·x) ----
// R22 lesson: the row-gather stream is CONCURRENCY-bound -- needs the full
// 20000-wave TLP of this dedicated dispatch. Keep separate.
__global__ __launch_bounds__(256) void k_prop(const u16* __restrict__ x, int ldx,
                                              u16* __restrict__ out,
                                              const int* __restrict__ offs,
                                              const int2* __restrict__ nbrs) {
    int c = __builtin_amdgcn_readfirstlane(blockIdx.x * 4 + (threadIdx.x >> 6));
    int lane = threadIdx.x & 63;
    int s = offs[c], e = offs[c + 1];
    float a0 = 0.f, a1 = 0.f, a2 = 0.f, a3 = 0.f;
    for (int i = s; i < e; i += 16) {
        int2 mm[16];
        ushort4 xv[16];
        bool g1 = (i + 4 < e), g2 = (i + 8 < e), g3 = (i + 12 < e);  // wave-uniform
#pragma unroll
        for (int j = 0; j < 4; j++) mm[j] = nbrs[i + j];
        if (g1) {
#pragma unroll
            for (int j = 4; j < 8; j++) mm[j] = nbrs[i + j];
        }
        if (g2) {
#pragma unroll
            for (int j = 8; j < 12; j++) mm[j] = nbrs[i + j];
        }
        if (g3) {
#pragma unroll
            for (int j = 12; j < 16; j++) mm[j] = nbrs[i + j];
        }
#pragma unroll
        for (int j = 0; j < 4; j++)
            xv[j] = *(const ushort4*)(x + (size_t)mm[j].x * ldx + lane * 4);
        if (g1) {
#pragma unroll
            for (int j = 4; j < 8; j++)
                xv[j] = *(const ushort4*)(x + (size_t)mm[j].x * ldx + lane * 4);
        }
        if (g2) {
#pragma unroll
            for (int j = 8; j < 12; j++)
                xv[j] = *(const ushort4*)(x + (size_t)mm[j].x * ldx + lane * 4);
        }
        if (g3) {
#pragma unroll
            for (int j = 12; j < 16; j++)
                xv[j] = *(const ushort4*)(x + (size_t)mm[j].x * ldx + lane * 4);
        }
#pragma unroll
        for (int j = 0; j < 4; j++) {
            float w = (i + j < e) ? __int_as_float(mm[j].y) : 0.f;
            a0 += w * bf2f(xv[j].x);
            a1 += w * bf2f(xv[j].y);
            a2 += w * bf2f(xv[j].z);
            a3 += w * bf2f(xv[j].w);
        }
        if (g1) {
#pragma unroll
            for (int j = 4; j < 8; j++) {
                float w = (i + j < e) ? __int_as_float(mm[j].y) : 0.f;
                a0 += w * bf2f(xv[j].x);
                a1 += w * bf2f(xv[j].y);
                a2 += w * bf2f(xv[j].z);
                a3 += w * bf2f(xv[j].w);
            }
        }
        if (g2) {
#pragma unroll
            for (int j = 8; j < 12; j++) {
                float w = (i + j < e) ? __int_as_float(mm[j].y) : 0.f;
                a0 += w * bf2f(xv[j].x);
                a1 += w * bf2f(xv[j].y);
                a2 += w * bf2f(xv[j].z);
                a3 += w * bf2f(xv[j].w);
            }
        }
        if (g3) {
#pragma unroll
            for (int j = 12; j < 16; j++) {
                float w = (i + j < e) ? __int_as_float(mm[j].y) : 0.f;
                a0 += w * bf2f(xv[j].x);
                a1 += w * bf2f(xv[j].y);
                a2 += w * bf2f(xv[j].z);
                a3 += w * bf2f(xv[j].w);
            }
        }
    }
    ushort4 o;
    o.x = f2bf(a0); o.y = f2bf(a1); o.z = f2bf(a2); o.w = f2bf(a3);
    *(ushort4*)(out + (size_t)c * 256 + lane * 4) = o;
}

// ---- R25 MFMA GEMM: tile M=32 x N=256, 4 waves, __launch_bounds__(256,4) ----
// R14 (2 blocks/CU, 8 waves/CU) was +8us over 128-thr; occupancy is the one
// gemm lever that moved. Now 4 blocks/CU (16 waves/CU, 4 waves/SIMD; VGPR
// cap 128 -- kernel ~100). LDS 26.6 KB x4 = 106 KB < 160. All else
// byte-identical to the R14 PASS. Waves 0-1 stage A-frags; head waits:
// even0 vmcnt(2), odd0 vmcnt(6), steady vmcnt(10); safety anchored by
// comp(s-1)'s implicit B-reg wait retiring A(s) before the iter-s barrier.
// mode 0: relu -> jk slice. mode 2: fused layer-3 + classifier.
__global__ __launch_bounds__(256, 4) void k_gemm(
    const u16* __restrict__ A0, const u16* __restrict__ A1,
    const u16* __restrict__ A2,
    int lda0, int lda1, int lda2,
    int K, const u16* __restrict__ Bf, const u16* __restrict__ Bf2,
    const u16* __restrict__ jkb,
    int mode,
    u16* __restrict__ outb, int ldob,
    const float* __restrict__ bias, const float* __restrict__ sc,
    const float* __restrict__ sh,
    const float* __restrict__ w2, const float* __restrict__ b2,
    float* __restrict__ outlog) {
    // u16 units: A-bufs [0,4096) 4 x 2KB. mode0: Cs 4 waves x [32][72]
    // at [4096, 4096+9216). mode2: H3 [32][264] at [4096, 12544).
    __shared__ __align__(16) u16 lds[13312];  // 26624 B
    int t = threadIdx.x;
    int wv = t >> 6, l = t & 63;
    int q = l >> 4, l16 = l & 15;
    int m0 = blockIdx.x * 32;
    int n0 = wv * 64;
    const int steps = K >> 5;  // 24

    f32x4 acc[2][4] = {};  // [mh][nt]

    int arow = m0 + min(wv, 1) * 16 + l16;  // staging rows (waves 0-1 only)

    auto stageA = [&](int buf, int s) {
        if (wv >= 2) return;
        int kt = s * 32;
        int ch = kt >> 8;  // wave-uniform -> SGPR select
        const u16* ap;
        int la;
        if (ch == 0) { ap = A0; la = lda0; }
        else if (ch == 1) { ap = A1; la = lda1; }
        else { ap = A2; la = lda2; }
        gll16(ap + (size_t)arow * la + (kt & 255) + q * 8, lds + buf * 1024 + wv * 512);
    };

    const u16* bfw = Bf + (size_t)(wv * 4) * 512 + l * 8;  // wave frag base + lane
    auto loadB = [&](bf16x8* dst, int s) {
#pragma unroll
        for (int j = 0; j < 4; j++)
            dst[j] = *(const bf16x8*)(bfw + (size_t)s * 8192 + j * 512);
    };
    auto comp = [&](int buf, const bf16x8* b) {
        const u16* base = lds + buf * 1024;
        bf16x8 a[2];
#pragma unroll
        for (int mh = 0; mh < 2; mh++)
            a[mh] = *(const bf16x8*)(base + mh * 512 + l * 8);
#pragma unroll
        for (int mh = 0; mh < 2; mh++)
#pragma unroll
            for (int j = 0; j < 4; j++)
                acc[mh][j] =
                    __builtin_amdgcn_mfma_f32_16x16x32_bf16(a[mh], b[j], acc[mh][j], 0, 0, 0);
    };

    bf16x8 bA[4], bB[4];
    loadB(bA, 0);            // B(0) first: A queue stays behind it
    stageA(0, 0);
    stageA(1, 1);
    stageA(2, 2);
    for (int s = 0; s < steps; s += 2) {
        if (s == 0)               asm volatile("s_waitcnt vmcnt(2)" ::: "memory");
        else                      asm volatile("s_waitcnt vmcnt(10)" ::: "memory");
        __builtin_amdgcn_s_barrier();
        __builtin_amdgcn_sched_barrier(0);
        loadB(bB, s + 1);
        __builtin_amdgcn_sched_barrier(0);
        if (s + 3 < steps) stageA((s + 3) & 3, s + 3);
        __builtin_amdgcn_sched_barrier(0);
        comp(s & 3, bA);
        if (s == 0)               asm volatile("s_waitcnt vmcnt(6)" ::: "memory");
        else                      asm volatile("s_waitcnt vmcnt(10)" ::: "memory");
        __builtin_amdgcn_s_barrier();
        __builtin_amdgcn_sched_barrier(0);
        if (s + 2 < steps) loadB(bA, s + 2);
        __builtin_amdgcn_sched_barrier(0);
        if (s + 4 < steps) stageA((s + 4) & 3, s + 4);
        __builtin_amdgcn_sched_barrier(0);
        comp((s + 1) & 3, bB);
    }
    __syncthreads();  // all waves done with K-loop LDS; reuse below

    if (mode == 0) {
        u16* Cs = lds + 4096 + wv * 2304;  // per-wave [32][72] u16
#pragma unroll
        for (int mh = 0; mh < 2; mh++)
#pragma unroll
            for (int j = 0; j < 4; j++)
#pragma unroll
                for (int i = 0; i < 4; i++) {
                    float v = acc[mh][j][i];
                    v = v > 0.f ? v : 0.f;
                    Cs[(mh * 16 + q * 4 + i) * 72 + j * 16 + l16] = f2bf(v);
                }
        // same-wave ds_write->ds_read ordered via lgkmcnt. 32x64 = 256 chunks.
#pragma unroll
        for (int jj = 0; jj < 4; jj++) {
            int f = jj * 64 + l;
            int r = f >> 3, cc = (f & 7) * 8;
            uint4 cv = *(const uint4*)&Cs[r * 72 + cc];
            int row = m0 + r;
            if (row < NN) *(uint4*)(outb + (size_t)row * ldob + n0 + cc) = cv;
        }
        return;
    }

    // ---- mode 2: fused classifier ----
    // h3 (relu, bf16) -> shared LDS [32][264]; wave wv writes its 64-col slice
    u16* Csh = lds + 4096;
#pragma unroll
    for (int mh = 0; mh < 2; mh++)
#pragma unroll
        for (int j = 0; j < 4; j++)
#pragma unroll
            for (int i = 0; i < 4; i++) {
                float v = acc[mh][j][i];
                v = v > 0.f ? v : 0.f;
                Csh[(mh * 16 + q * 4 + i) * 264 + n0 + j * 16 + l16] = f2bf(v);
            }
    __syncthreads();  // h3 visible to all waves

#pragma unroll
    for (int mh = 0; mh < 2; mh++)
#pragma unroll
        for (int j = 0; j < 4; j++)
            acc[mh][j] = (f32x4){0.f, 0.f, 0.f, 0.f};

    // phase B: z = [jk0,jk1,jk2,h3] @ w1T (K=1024: 24 piped + 8 h3-LDS steps)
    const u16* bfw2 = Bf2 + (size_t)(wv * 4) * 512 + l * 8;
    auto loadB2 = [&](bf16x8* dst, int s) {
#pragma unroll
        for (int j = 0; j < 4; j++)
            dst[j] = *(const bf16x8*)(bfw2 + (size_t)s * 8192 + j * 512);
    };
    auto stageB = [&](int buf, int s) {
        if (wv >= 2) return;
        int kt = s * 32;
        const u16* ap = jkb + (size_t)(kt >> 8) * 256;
        gll16(ap + (size_t)arow * 1024 + (kt & 255) + q * 8, lds + buf * 1024 + wv * 512);
    };
    auto comph = [&](int ss, const bf16x8* b) {
        bf16x8 a[2];
#pragma unroll
        for (int mh = 0; mh < 2; mh++)
            a[mh] = *(const bf16x8*)(Csh + (mh * 16 + l16) * 264 + ss * 32 + q * 8);
#pragma unroll
        for (int mh = 0; mh < 2; mh++)
#pragma unroll
            for (int j = 0; j < 4; j++)
                acc[mh][j] =
                    __builtin_amdgcn_mfma_f32_16x16x32_bf16(a[mh], b[j], acc[mh][j], 0, 0, 0);
    };

    loadB2(bA, 0);
    stageB(0, 0);
    stageB(1, 1);
    stageB(2, 2);
    for (int s = 0; s < 24; s += 2) {
        if (s == 0)               asm volatile("s_waitcnt vmcnt(2)" ::: "memory");
        else                      asm volatile("s_waitcnt vmcnt(10)" ::: "memory");
        __builtin_amdgcn_s_barrier();
        __builtin_amdgcn_sched_barrier(0);
        loadB2(bB, s + 1);
        __builtin_amdgcn_sched_barrier(0);
        if (s + 3 < 24) stageB((s + 3) & 3, s + 3);
        __builtin_amdgcn_sched_barrier(0);
        comp(s & 3, bA);
        if (s == 0)               asm volatile("s_waitcnt vmcnt(6)" ::: "memory");
        else                      asm volatile("s_waitcnt vmcnt(10)" ::: "memory");
        __builtin_amdgcn_s_barrier();
        __builtin_amdgcn_sched_barrier(0);
        loadB2(bA, s + 2);  // s+2 <= 24 < 32 always valid
        __builtin_amdgcn_sched_barrier(0);
        if (s + 4 < 24) stageB((s + 4) & 3, s + 4);
        __builtin_amdgcn_sched_barrier(0);
        comp((s + 1) & 3, bB);
    }
    // h3 steps: no barriers, no manual waits (h3 LDS read-only; B regs
    // auto-waited; A-bufs untouched).
    for (int s = 24; s < 32; s += 2) {
        loadB2(bB, s + 1);
        comph(s - 24, bA);
        if (s + 2 < 32) loadB2(bA, s + 2);
        comph(s - 23, bB);
    }

    // classifier epilogue: +b1, relu, BN affine, @w2 + b2 -> logits
    {
        float bi[4], s4[4], h4[4], wa[4], wb[4];
#pragma unroll
        for (int j = 0; j < 4; j++) {
            int col = n0 + j * 16 + l16;
            bi[j] = bias[col];
            s4[j] = sc[col];
            h4[j] = sh[col];
            wa[j] = w2[2 * col];
            wb[j] = w2[2 * col + 1];
        }
        float* red = (float*)lds;  // A-buf area: [4 waves][32 rows][2] floats
#pragma unroll
        for (int mh = 0; mh < 2; mh++)
#pragma unroll
            for (int i = 0; i < 4; i++) {
                float p0 = 0.f, p1 = 0.f;
#pragma unroll
                for (int j = 0; j < 4; j++) {
                    float v = acc[mh][j][i] + bi[j];
                    v = v > 0.f ? v : 0.f;
                    v = v * s4[j] + h4[j];
                    p0 += v * wa[j];
                    p1 += v * wb[j];
                }
#pragma unroll
                for (int off = 1; off < 16; off <<= 1) {
                    p0 += __shfl_xor(p0, off, 64);
                    p1 += __shfl_xor(p1, off, 64);
                }
                if (l16 == 0) {
                    int rl = mh * 16 + q * 4 + i;
                    red[(wv * 32 + rl) * 2 + 0] = p0;
                    red[(wv * 32 + rl) * 2 + 1] = p1;
                }
            }
        __syncthreads();
        if (t < 64) {
            int rl = t >> 1, cp = t & 1;
            float v = red[(0 * 32 + rl) * 2 + cp] + red[(1 * 32 + rl) * 2 + cp] +
                      red[(2 * 32 + rl) * 2 + cp] + red[(3 * 32 + rl) * 2 + cp];
            int row = m0 + rl;
            if (row < NN) outlog[(size_t)row * 2 + cp] = v + b2[cp];
        }
    }
}

extern "C" void kernel_launch(void* const* d_in, const int* in_sizes, int n_in,
                              void* d_out, int out_size, void* d_ws, size_t ws_size,
                              hipStream_t stream) {
    const float* features = (const float*)d_in[0];
    const int* ei = (const int*)d_in[1];
    // d_in[2] = edgenet_input (bypassed by edge_weight_override)
    const float* ew = (const float*)d_in[3];
    const float* cheb_w = (const float*)d_in[4];
    const float* w1 = (const float*)d_in[5];
    const float* b1 = (const float*)d_in[6];
    const float* g = (const float*)d_in[7];
    const float* be = (const float*)d_in[8];
    const float* mn = (const float*)d_in[9];
    const float* vr = (const float*)d_in[10];
    const float* w2 = (const float*)d_in[11];
    const float* b2 = (const float*)d_in[12];
    float* out = (float*)d_out;  // [NN*2] logits, then [EE] ew

    char* p = (char*)d_ws;
    auto alloc = [&](size_t bytes) -> char* {
        char* r = p;
        p += (bytes + 255) & ~(size_t)255;
        return r;
    };
    float* deg = (float*)alloc((size_t)NN * 4);
    int* counts = (int*)alloc((size_t)(NN + 1) * 4);
    int* cursor = (int*)alloc((size_t)NN * 4);
    size_t zero_bytes = (size_t)(p - (char*)deg);
    int* offs = (int*)alloc((size_t)(NN + 1) * 4);
    int2* nbrs = (int2*)alloc((size_t)(EE + 16) * 8);
    u16* xb = (u16*)alloc((size_t)NN * 256 * 2);
    u16* tx1 = (u16*)alloc((size_t)NN * 256 * 2);
    u16* yb = (u16*)alloc((size_t)NN * 256 * 2);   // y = L·tx1 (fold consumes raw)
    u16* jk = (u16*)alloc((size_t)NN * 1024 * 2);
    u16* chebT = (u16*)alloc((size_t)LGN * 3 * 256 * 256 * 2);  // folded, frag-tiled
    u16* w1T = (u16*)alloc((size_t)1024 * 256 * 2);             // frag-tiled
    float* sc = (float*)alloc(256 * 4);
    float* sh = (float*)alloc(256 * 4);

    hipMemsetAsync(deg, 0, zero_bytes, stream);
    k_edge1<<<(EE + 255) / 256, 256, 0, stream>>>(ei, ew, deg, counts, out + (size_t)NN * 2,
                                                  nbrs);
    k_scan<<<1, 1024, 0, stream>>>(counts, offs);
    k_scatter<<<(EE + 255) / 256, 256, 0, stream>>>(ei, ew, deg, offs, cursor, nbrs);
    const int prep_items = NN * 256 + 4 * 24576 + 32768 + 256;
    k_prep<<<(prep_items + 255) / 256, 256, 0, stream>>>(features, xb, cheb_w, chebT, w1, w1T,
                                                         g, be, mn, vr, sc, sh);

    const int gg = (NN + 31) / 32;  // 625 blocks (tile M=32 x N=256, 256 thr)
    for (int i = 0; i < LGN; i++) {
        const u16* x = (i == 0) ? xb : (jk + (size_t)(i - 1) * 256);
        int ldx = (i == 0) ? 256 : 1024;
        k_prop<<<NN / 4, 256, 0, stream>>>(x, ldx, tx1, offs, nbrs);
        k_prop<<<NN / 4, 256, 0, stream>>>(tx1, 256, yb, offs, nbrs);
        if (i < LGN - 1) {
            k_gemm<<<gg, 256, 0, stream>>>(
                x, tx1, yb, ldx, 256, 256, 768, chebT + (size_t)i * 256 * 768,
                (const u16*)nullptr, (const u16*)nullptr, 0, jk + (size_t)i * 256, 1024,
                (const float*)nullptr, (const float*)nullptr, (const float*)nullptr,
                (const float*)nullptr, (const float*)nullptr, (float*)nullptr);
        } else {
            // fused layer-3 cheb gemm + classifier (mode 2)
            k_gemm<<<gg, 256, 0, stream>>>(
                x, tx1, yb, ldx, 256, 256, 768, chebT + (size_t)i * 256 * 768,
                w1T, jk, 2, (u16*)nullptr, 0, b1, sc, sh, w2, b2, out);
        }
    }
}